// Round 4
// baseline (26327.979 us; speedup 1.0000x reference)
//
#include <hip/hip_runtime.h>
#include <cfloat>

// Problem constants
#define B_SZ 32768
#define K_SZ 8192
#define D_SZ 512

static constexpr float DECAY = 0.99f;
static constexpr float OMD   = 1.0f - 0.99f;   // (1 - decay) in fp32
static constexpr float EPS   = 1e-5f;

// ---------------------------------------------------------------------------
// Kernel A: row sum-of-squares. One wave per row (D=512).
// ---------------------------------------------------------------------------
__global__ __launch_bounds__(256)
void rowsq_kernel(const float* __restrict__ src, float* __restrict__ dst) {
    const int wave = threadIdx.x >> 6;
    const int lane = threadIdx.x & 63;
    const int r = blockIdx.x * 4 + wave;
    const float* row = src + (size_t)r * D_SZ;
    float s = 0.f;
#pragma unroll
    for (int i = 0; i < 2; ++i) {
        float4 v = *reinterpret_cast<const float4*>(row + i * 256 + lane * 4);
        s += v.x * v.x + v.y * v.y + v.z * v.z + v.w * v.w;
    }
#pragma unroll
    for (int off = 32; off >= 1; off >>= 1) s += __shfl_xor(s, off);
    if (lane == 0) dst[r] = s;
}

// ---------------------------------------------------------------------------
// Kernel B: EMA init. o_nemcb = DECAY*ema_cb; o_ncs = DECAY*ema_cs.
// ---------------------------------------------------------------------------
__global__ __launch_bounds__(256)
void init_ema_kernel(const float* __restrict__ ema_cb,
                     const float* __restrict__ ema_cs,
                     float* __restrict__ o_nemcb,
                     float* __restrict__ o_ncs) {
    const size_t i = (size_t)blockIdx.x * 256 + threadIdx.x;  // float4 index
    float4 e = *reinterpret_cast<const float4*>(ema_cb + i * 4);
    e.x *= DECAY; e.y *= DECAY; e.z *= DECAY; e.w *= DECAY;
    *reinterpret_cast<float4*>(o_nemcb + i * 4) = e;
    if (i < K_SZ) o_ncs[i] = DECAY * ema_cs[i];
}

// ---------------------------------------------------------------------------
// Kernel 1: distance argmin.  R4: 16x8 thread tile (0.75 B/FMA LDS traffic,
// was 1.0), VGPR staging (R3's global_load_lds destroyed L2/L3 residency:
// FETCH 0.47 -> 13.4 GB; reverted), direct component FMAs (no unpack movs).
//
// Grid: 128 row-blocks x 64 col-blocks (cb fast -> same cache-friendly
// order as R0-R2). Block 256 thr = 4 waves; tile 256 rows x 128 cols.
//   thread rows: tr*16 .. +15 (tr = lane&15)
//   thread cols: wid*32 + cg*8 .. +7 (cg = lane>>4)
//
// LDS: d-major planes, chunk = 16 d, double-buffered:
//   per buffer: z planes 16 x 256 floats (1024 B), then c planes 16 x 128
//   floats (512 B) = 24 KB; 2 buffers = 48 KB.
// Conflict scheme (R2-proven family): granule g (16 B) of a plane stored at
// position sigma(g) ^ h, h = d>>2 (0..3).
//   z: sigma(g) = (g>>2) + ((g&3)<<4)   (g 0..63)
//   c: sigma(g) = (g>>1) + ((g&1)<<4)   (g 0..31)
// Reads per d: a = 4 x b128 at pos (tr^h) + 16j -> 16 addrs spread over 8
//   bank-quads x 2 (free) with 4-lane broadcast; b = 2 x b128 at pos
//   ((4wid+cg)^h) + 16j -> 16-lane broadcast (free).
// Staging writes: 24 b32/thread/chunk, ~4-way (small fraction, accepted).
//
// Pipeline: 1 barrier/chunk. Writes go to buf^1 whose readers finished at
// the previous barrier; global loads for t+1 issued before compute of t.
//
// Accumulation: per acc[r][c], d ascends 0..511 (x,y,z,w in float4, q, h,
// chunks ascending) -> bit-identical scores to all prior rounds ->
// identical indices.
// ---------------------------------------------------------------------------
__global__ __launch_bounds__(256, 2)
void argmin_kernel(const float* __restrict__ z_e,
                   const float* __restrict__ codebook,
                   const float* __restrict__ c_sq,
                   const float* __restrict__ z_sq,
                   float2* __restrict__ partials)   // [B][64]
{
    __shared__ float sm[2][6144];        // 48 KB: [buf][z 4096 | c 2048]

    const int tid  = threadIdx.x;
    const int wid  = tid >> 6;
    const int lane = tid & 63;
    const int tr   = lane & 15;          // row group: rows tr*16..+15
    const int cg   = lane >> 4;          // col group within wave
    const int c0l  = wid * 32 + cg * 8;  // local col base (0..120)

    const int rb = blockIdx.x >> 6;      // row block 0..127
    const int cb = blockIdx.x & 63;      // col block 0..63
    const int b0 = rb * 256;
    const int k0 = cb * 128;

    float acc[16][8];
#pragma unroll
    for (int r = 0; r < 16; ++r)
#pragma unroll
        for (int c = 0; c < 8; ++c) acc[r][c] = 0.f;

    // ---- Hoisted staging descriptors ----
    // z: lin = it*256+tid (it 0..3): d4 = tid&3, n = it*64 + (tid>>2) (0..255)
    // c: lin = it*256+tid (it 0..1): d4 = tid&3, n = it*64 + (tid>>2) (0..127)
    // write pos = sigma(n>>2) ^ d4  (h = d>>2 = d4 for all 4 k of the float4)
    const float* gz[4]; int wz[4];
    const float* gc[2]; int wc[2];
    {
        const int d4 = tid & 3;
#pragma unroll
        for (int it = 0; it < 4; ++it) {
            const int n = it * 64 + (tid >> 2);
            const int g = n >> 2;
            const int sz = (g >> 2) + ((g & 3) << 4);
            wz[it] = d4 * 4 * 1024 + (((sz ^ d4) << 4)) + (n & 3) * 4;
            gz[it] = z_e + (size_t)(b0 + n) * D_SZ + d4 * 4;
        }
#pragma unroll
        for (int it = 0; it < 2; ++it) {
            const int n = it * 64 + (tid >> 2);
            const int g = n >> 2;
            const int sc = (g >> 1) + ((g & 1) << 4);
            wc[it] = 16384 + d4 * 4 * 512 + (((sc ^ d4) << 4)) + (n & 3) * 4;
            gc[it] = codebook + (size_t)(k0 + n) * D_SZ + d4 * 4;
        }
    }
    const int tr4 = tr << 4;             // a-read base bits
    const int wc4 = (4 * wid + cg) << 4; // b-read base bits

    float4 vz[4], vc[2];
#define GLOAD(t)                                                              \
    {                                                                         \
        _Pragma("unroll")                                                     \
        for (int i = 0; i < 4; ++i)                                           \
            vz[i] = *reinterpret_cast<const float4*>(gz[i] + (t) * 16);       \
        _Pragma("unroll")                                                     \
        for (int i = 0; i < 2; ++i)                                           \
            vc[i] = *reinterpret_cast<const float4*>(gc[i] + (t) * 16);       \
    }
#define WSTAGE(bf)                                                            \
    {                                                                         \
        char* bp = reinterpret_cast<char*>(&sm[bf][0]);                       \
        _Pragma("unroll")                                                     \
        for (int i = 0; i < 4; ++i) {                                         \
            char* p = bp + wz[i];                                             \
            *reinterpret_cast<float*>(p + 0)    = vz[i].x;                    \
            *reinterpret_cast<float*>(p + 1024) = vz[i].y;                    \
            *reinterpret_cast<float*>(p + 2048) = vz[i].z;                    \
            *reinterpret_cast<float*>(p + 3072) = vz[i].w;                    \
        }                                                                     \
        _Pragma("unroll")                                                     \
        for (int i = 0; i < 2; ++i) {                                         \
            char* p = bp + wc[i];                                             \
            *reinterpret_cast<float*>(p + 0)    = vc[i].x;                    \
            *reinterpret_cast<float*>(p + 512)  = vc[i].y;                    \
            *reinterpret_cast<float*>(p + 1024) = vc[i].z;                    \
            *reinterpret_cast<float*>(p + 1536) = vc[i].w;                    \
        }                                                                     \
    }

    GLOAD(0);
    WSTAGE(0);
    __syncthreads();

#pragma unroll 1
    for (int t = 0; t < 32; ++t) {
        const int cur = t & 1;
        if (t < 31) GLOAD(t + 1);

        const char* zb  = reinterpret_cast<const char*>(&sm[cur][0]);
        const char* cbb = zb + 16384;
#pragma unroll
        for (int h = 0; h < 4; ++h) {
            const int ax = tr4 ^ (h << 4);
            const int bx = wc4 ^ (h << 4);
#pragma unroll
            for (int q = 0; q < 4; ++q) {
                const int d = h * 4 + q;
                const float4 a0 = *reinterpret_cast<const float4*>(zb  + ax + d * 1024 + 0);
                const float4 a1 = *reinterpret_cast<const float4*>(zb  + ax + d * 1024 + 256);
                const float4 a2 = *reinterpret_cast<const float4*>(zb  + ax + d * 1024 + 512);
                const float4 a3 = *reinterpret_cast<const float4*>(zb  + ax + d * 1024 + 768);
                const float4 q0 = *reinterpret_cast<const float4*>(cbb + bx + d * 512 + 0);
                const float4 q1 = *reinterpret_cast<const float4*>(cbb + bx + d * 512 + 256);
#define FMAS(R, AV)                                                           \
                acc[R][0] = fmaf(AV, q0.x, acc[R][0]);                        \
                acc[R][1] = fmaf(AV, q0.y, acc[R][1]);                        \
                acc[R][2] = fmaf(AV, q0.z, acc[R][2]);                        \
                acc[R][3] = fmaf(AV, q0.w, acc[R][3]);                        \
                acc[R][4] = fmaf(AV, q1.x, acc[R][4]);                        \
                acc[R][5] = fmaf(AV, q1.y, acc[R][5]);                        \
                acc[R][6] = fmaf(AV, q1.z, acc[R][6]);                        \
                acc[R][7] = fmaf(AV, q1.w, acc[R][7]);
                FMAS(0,  a0.x) FMAS(1,  a0.y) FMAS(2,  a0.z) FMAS(3,  a0.w)
                FMAS(4,  a1.x) FMAS(5,  a1.y) FMAS(6,  a1.z) FMAS(7,  a1.w)
                FMAS(8,  a2.x) FMAS(9,  a2.y) FMAS(10, a2.z) FMAS(11, a2.w)
                FMAS(12, a3.x) FMAS(13, a3.y) FMAS(14, a3.z) FMAS(15, a3.w)
#undef FMAS
            }
        }
        if (t < 31) WSTAGE(cur ^ 1);   // readers of buf^1 finished at t-1's barrier
        __syncthreads();
    }
#undef GLOAD
#undef WSTAGE

    // ---- Epilogue: d2 + per-row argmin over this block's 128 cols ----
    float zq[16], cq[8];
#pragma unroll
    for (int j = 0; j < 16; ++j) zq[j] = z_sq[b0 + tr * 16 + j];
#pragma unroll
    for (int j = 0; j < 8; ++j) cq[j] = c_sq[k0 + c0l + j];

    float mv[16];
    int   mi[16];
#pragma unroll
    for (int r = 0; r < 16; ++r) {
        mv[r] = FLT_MAX; mi[r] = 0;
#pragma unroll
        for (int c = 0; c < 8; ++c) {
            float s = fmaf(-2.f, acc[r][c], zq[r]) + cq[c];
            if (s < mv[r]) { mv[r] = s; mi[r] = k0 + c0l + c; }
        }
        // merge across the 4 col-groups of this wave
#pragma unroll
        for (int off = 16; off <= 32; off <<= 1) {
            float v2 = __shfl_xor(mv[r], off);
            int   i2 = __shfl_xor(mi[r], off);
            if (v2 < mv[r] || (v2 == mv[r] && i2 < mi[r])) { mv[r] = v2; mi[r] = i2; }
        }
    }

    // mbuf aliases the dead staging LDS; last loop barrier protects it.
    float (*mbuf)[256][2] = reinterpret_cast<float (*)[256][2]>(&sm[0][0]);
    if (cg == 0) {
#pragma unroll
        for (int r = 0; r < 16; ++r) {
            mbuf[wid][tr * 16 + r][0] = mv[r];
            mbuf[wid][tr * 16 + r][1] = (float)mi[r];
        }
    }
    __syncthreads();
    // merge the 4 waves (ascending wid = ascending col -> first-min semantics)
    {
        float v = mbuf[0][tid][0];
        int   idx = (int)mbuf[0][tid][1];
#pragma unroll
        for (int w = 1; w < 4; ++w) {
            float v2 = mbuf[w][tid][0];
            int   i2 = (int)mbuf[w][tid][1];
            if (v2 < v || (v2 == v && i2 < idx)) { v = v2; idx = i2; }
        }
        partials[(size_t)(b0 + tid) * 64 + cb] = make_float2(v, (float)idx);
    }
}

// ---------------------------------------------------------------------------
// Kernel 1b: reduce 64 col-block partials per row -> final index.
// ---------------------------------------------------------------------------
__global__ __launch_bounds__(256)
void reduce_kernel(const float2* __restrict__ partials,
                   float* __restrict__ out_idx_f) {
    const int row  = blockIdx.x * 4 + (threadIdx.x >> 6);
    const int lane = threadIdx.x & 63;
    float2 p = partials[(size_t)row * 64 + lane];
    float v = p.x;
    int idx = (int)p.y;
#pragma unroll
    for (int off = 32; off >= 1; off >>= 1) {
        float v2 = __shfl_xor(v, off);
        int   i2 = __shfl_xor(idx, off);
        if (v2 < v || (v2 == v && i2 < idx)) { v = v2; idx = i2; }
    }
    if (lane == 0) out_idx_f[row] = (float)idx;
}

// ---------------------------------------------------------------------------
// Kernel 2: gather z_q + scatter EMA contributions into the outputs.
// ---------------------------------------------------------------------------
__global__ __launch_bounds__(256)
void scatter_kernel(const float* __restrict__ z_e,
                    const float* __restrict__ codebook,
                    const float* __restrict__ out_idx_f,
                    float* __restrict__ z_q,
                    float* __restrict__ o_ncs,
                    float* __restrict__ o_nemcb)
{
    const int wave = threadIdx.x >> 6;
    const int lane = threadIdx.x & 63;
    const int b = blockIdx.x * 4 + wave;
    const int idx = (int)out_idx_f[b];
#pragma unroll
    for (int i = 0; i < 2; ++i) {
        int d = i * 256 + lane * 4;
        float4 cq = *reinterpret_cast<const float4*>(
            codebook + (size_t)idx * D_SZ + d);
        *reinterpret_cast<float4*>(z_q + (size_t)b * D_SZ + d) = cq;
        float4 zv = *reinterpret_cast<const float4*>(
            z_e + (size_t)b * D_SZ + d);
        atomicAdd(o_nemcb + (size_t)idx * D_SZ + d + 0, OMD * zv.x);
        atomicAdd(o_nemcb + (size_t)idx * D_SZ + d + 1, OMD * zv.y);
        atomicAdd(o_nemcb + (size_t)idx * D_SZ + d + 2, OMD * zv.z);
        atomicAdd(o_nemcb + (size_t)idx * D_SZ + d + 3, OMD * zv.w);
    }
    if (lane == 0) atomicAdd(o_ncs + idx, OMD);
}

// ---------------------------------------------------------------------------
// Kernel 3: new_codebook = new_ema_codebook / (new_cluster_size + EPS).
// ---------------------------------------------------------------------------
__global__ __launch_bounds__(256)
void finalize_kernel(const float* __restrict__ o_nemcb,
                     const float* __restrict__ o_ncs,
                     float* __restrict__ o_ncb)
{
    const size_t i = (size_t)blockIdx.x * 256 + threadIdx.x;  // float4 index
    const int k = (int)(i >> 7);
    float4 nem = *reinterpret_cast<const float4*>(o_nemcb + i * 4);
    float den = o_ncs[k] + EPS;
    float4 ncb;
    ncb.x = nem.x / den; ncb.y = nem.y / den;
    ncb.z = nem.z / den; ncb.w = nem.w / den;
    *reinterpret_cast<float4*>(o_ncb + i * 4) = ncb;
}

// ---------------------------------------------------------------------------
extern "C" void kernel_launch(void* const* d_in, const int* in_sizes, int n_in,
                              void* d_out, int out_size, void* d_ws, size_t ws_size,
                              hipStream_t stream) {
    const float* z_e      = (const float*)d_in[0];   // (B, D)
    const float* codebook = (const float*)d_in[1];   // (K, D)
    const float* ema_cs   = (const float*)d_in[2];   // (K,)
    const float* ema_cb   = (const float*)d_in[3];   // (K, D)

    float* out = (float*)d_out;
    float* o_zq    = out;                                  // B*D
    float* o_idx   = out + (size_t)B_SZ * D_SZ;            // B
    float* o_ncb   = o_idx + B_SZ;                         // K*D
    float* o_ncs   = o_ncb + (size_t)K_SZ * D_SZ;          // K
    float* o_nemcb = o_ncs + K_SZ;                         // K*D

    // Scratch parked inside o_zq (overwritten by scatter_kernel afterwards).
    float2* w_part = (float2*)o_zq;
    float*  w_csq  = o_zq + (size_t)B_SZ * 64 * 2;
    float*  w_zsq  = w_csq + K_SZ;

    rowsq_kernel<<<K_SZ / 4, 256, 0, stream>>>(codebook, w_csq);
    rowsq_kernel<<<B_SZ / 4, 256, 0, stream>>>(z_e, w_zsq);
    init_ema_kernel<<<K_SZ * D_SZ / 4 / 256, 256, 0, stream>>>(
        ema_cb, ema_cs, o_nemcb, o_ncs);
    argmin_kernel<<<(B_SZ / 256) * (K_SZ / 128), 256, 0, stream>>>(
        z_e, codebook, w_csq, w_zsq, w_part);
    reduce_kernel<<<B_SZ / 4, 256, 0, stream>>>(w_part, o_idx);
    scatter_kernel<<<B_SZ / 4, 256, 0, stream>>>(z_e, codebook, o_idx,
                                                 o_zq, o_ncs, o_nemcb);
    finalize_kernel<<<K_SZ * D_SZ / 4 / 256, 256, 0, stream>>>(
        o_nemcb, o_ncs, o_ncb);
}

// Round 6
// 3488.450 us; speedup vs baseline: 7.5472x; 7.5472x over previous
//
#include <hip/hip_runtime.h>
#include <cfloat>

// Problem constants
#define B_SZ 32768
#define K_SZ 8192
#define D_SZ 512

static constexpr float DECAY = 0.99f;
static constexpr float OMD   = 1.0f - 0.99f;   // (1 - decay) in fp32
static constexpr float EPS   = 1e-5f;

// ---------------------------------------------------------------------------
// Kernel A: row sum-of-squares. One wave per row (D=512).
// ---------------------------------------------------------------------------
__global__ __launch_bounds__(256)
void rowsq_kernel(const float* __restrict__ src, float* __restrict__ dst) {
    const int wave = threadIdx.x >> 6;
    const int lane = threadIdx.x & 63;
    const int r = blockIdx.x * 4 + wave;
    const float* row = src + (size_t)r * D_SZ;
    float s = 0.f;
#pragma unroll
    for (int i = 0; i < 2; ++i) {
        float4 v = *reinterpret_cast<const float4*>(row + i * 256 + lane * 4);
        s += v.x * v.x + v.y * v.y + v.z * v.z + v.w * v.w;
    }
#pragma unroll
    for (int off = 32; off >= 1; off >>= 1) s += __shfl_xor(s, off);
    if (lane == 0) dst[r] = s;
}

// ---------------------------------------------------------------------------
// Kernel B: EMA init. o_nemcb = DECAY*ema_cb; o_ncs = DECAY*ema_cs.
// ---------------------------------------------------------------------------
__global__ __launch_bounds__(256)
void init_ema_kernel(const float* __restrict__ ema_cb,
                     const float* __restrict__ ema_cs,
                     float* __restrict__ o_nemcb,
                     float* __restrict__ o_ncs) {
    const size_t i = (size_t)blockIdx.x * 256 + threadIdx.x;  // float4 index
    float4 e = *reinterpret_cast<const float4*>(ema_cb + i * 4);
    e.x *= DECAY; e.y *= DECAY; e.z *= DECAY; e.w *= DECAY;
    *reinterpret_cast<float4*>(o_nemcb + i * 4) = e;
    if (i < K_SZ) o_ncs[i] = DECAY * ema_cs[i];
}

// ---------------------------------------------------------------------------
// Kernel 1: distance argmin.  R5 (resubmit; prior round was an infra
// failure, kernel never ran) = R4's 16x8 tile idea, spill-proofed by
// returning to R2's proven skeleton:
//   - single LDS buffer, stage-inside-two-barriers (staging regs have a
//     ~10-inst live range; R4's prefetch-across-compute held 24 regs live
//     through the whole chunk and the allocator spilled acc -> 131 GB of
//     scratch HBM traffic),
//   - no conditional staging, plain  load / barrier / write / barrier /
//     compute  per chunk.
//
// Grid: 128 row-blocks x 64 col-blocks (cb fast). Block 256 thr = 4 waves;
// tile 256 rows x 128 cols; thread-tile 16x8:
//   rows tr*16..+15 (tr = lane&15), cols wid*32 + cg*8..+7 (cg = lane>>4).
// LDS bytes/FMA = (16+8)*4/128 = 0.75 (was 1.0) -> LDS-pipe cycles/CU drop
// from ~6.3e6 (81% busy, the top pipe R0-R2) to ~4.7e6.
//
// LDS: 24 KB, d-major planes, chunk = 16 d:
//   z planes: 16 x 256 floats (1 KB each);  c planes: 16 x 128 floats.
// Conflict scheme (R2 family), granule g = 16 B, plane-local position:
//   z: pos = sigma_z(g) ^ h,  sigma_z(g) = (g>>2) + ((g&3)<<4), h = d>>2
//   c: pos = sigma_c(g) ^ h,  sigma_c(g) = (g>>1) + ((g&1)<<4)
// a-reads per d: 4 x b128 at ((tr^h)<<4) + {0,256,512,768}: 8 bank-quads
//   x 2 + 4-lane broadcast = 2-way = free.  b-reads: 2 x b128 at
//   ((cc^h)<<4) + {0,256}, 16-lane broadcast, 4 distinct quads = free.
// Staging writes: 24 ds_write_b32/thread/chunk, z-path 4-way / c-path
//   2-way on a small op count (~1e5 insts/CU total) = accepted.
//
// Accumulation: per acc[r][c], d ascends 0..511 (chunks asc, h asc, q asc)
// -> bit-identical scores to R0-R2 -> identical indices.
// ---------------------------------------------------------------------------
__global__ __launch_bounds__(256, 2)
void argmin_kernel(const float* __restrict__ z_e,
                   const float* __restrict__ codebook,
                   const float* __restrict__ c_sq,
                   const float* __restrict__ z_sq,
                   float2* __restrict__ partials)   // [B][64]
{
    __shared__ float sm[16 * 256 + 16 * 128];   // 24 KB: z planes | c planes

    const int tid  = threadIdx.x;
    const int wid  = tid >> 6;
    const int lane = tid & 63;
    const int tr   = lane & 15;          // row group: rows tr*16..+15
    const int cg   = lane >> 4;          // col group within wave
    const int cc   = 4 * wid + cg;       // col block-pair index (0..15)
    const int c0l  = wid * 32 + cg * 8;  // local col base (0..120)

    const int rb = blockIdx.x >> 6;      // row block 0..127
    const int cb = blockIdx.x & 63;      // col block 0..63
    const int b0 = rb * 256;
    const int k0 = cb * 128;

    float acc[16][8];
#pragma unroll
    for (int r = 0; r < 16; ++r)
#pragma unroll
        for (int c = 0; c < 8; ++c) acc[r][c] = 0.f;

    // ---- Hoisted staging descriptors ----
    // z: it 0..3: d4 = tid&3, n = it*64 + (tid>>2) (rows 0..255)
    // c: it 0..1: same d4, n (rows 0..127)
    const float* gz[4]; int wz[4];
    const float* gc[2]; int wc[2];
    {
        const int d4 = tid & 3;
#pragma unroll
        for (int it = 0; it < 4; ++it) {
            const int n = it * 64 + (tid >> 2);
            const int g = n >> 2;
            const int sz = (g >> 2) + ((g & 3) << 4);
            wz[it] = d4 * 4096 + ((sz ^ d4) << 4) + (n & 3) * 4;  // byte off
            gz[it] = z_e + (size_t)(b0 + n) * D_SZ + d4 * 4;
        }
#pragma unroll
        for (int it = 0; it < 2; ++it) {
            const int n = it * 64 + (tid >> 2);
            const int g = n >> 2;
            const int sc = (g >> 1) + ((g & 1) << 4);
            wc[it] = 16384 + d4 * 2048 + ((sc ^ d4) << 4) + (n & 3) * 4;
            gc[it] = codebook + (size_t)(k0 + n) * D_SZ + d4 * 4;
        }
    }
    const int trx = tr << 4;             // a-read base bits (bytes)
    const int ccx = cc << 4;             // b-read base bits (bytes)
    char* smb = reinterpret_cast<char*>(&sm[0]);

#pragma unroll 1
    for (int t = 0; t < 32; ++t) {
        // ---- stage chunk t (short register live ranges) ----
        float4 vz0 = *reinterpret_cast<const float4*>(gz[0] + t * 16);
        float4 vz1 = *reinterpret_cast<const float4*>(gz[1] + t * 16);
        float4 vz2 = *reinterpret_cast<const float4*>(gz[2] + t * 16);
        float4 vz3 = *reinterpret_cast<const float4*>(gz[3] + t * 16);
        float4 vc0 = *reinterpret_cast<const float4*>(gc[0] + t * 16);
        float4 vc1 = *reinterpret_cast<const float4*>(gc[1] + t * 16);
        __syncthreads();   // previous chunk's readers done
#define WZ(V, I)                                                              \
        { char* p = smb + wz[I];                                              \
          *reinterpret_cast<float*>(p + 0)    = V.x;                          \
          *reinterpret_cast<float*>(p + 1024) = V.y;                          \
          *reinterpret_cast<float*>(p + 2048) = V.z;                          \
          *reinterpret_cast<float*>(p + 3072) = V.w; }
#define WC(V, I)                                                              \
        { char* p = smb + wc[I];                                              \
          *reinterpret_cast<float*>(p + 0)    = V.x;                          \
          *reinterpret_cast<float*>(p + 512)  = V.y;                          \
          *reinterpret_cast<float*>(p + 1024) = V.z;                          \
          *reinterpret_cast<float*>(p + 1536) = V.w; }
        WZ(vz0, 0) WZ(vz1, 1) WZ(vz2, 2) WZ(vz3, 3)
        WC(vc0, 0) WC(vc1, 1)
#undef WZ
#undef WC
        __syncthreads();

        // ---- compute chunk t: 16 d, fully unrolled ----
        const char* zb  = smb;
        const char* cbb = smb + 16384;
#pragma unroll
        for (int h = 0; h < 4; ++h) {
            const int xa = trx ^ (h << 4);
            const int xb = ccx ^ (h << 4);
#pragma unroll
            for (int q = 0; q < 4; ++q) {
                const int d = h * 4 + q;
                const float4 q0 = *reinterpret_cast<const float4*>(cbb + xb + d * 512 + 0);
                const float4 q1 = *reinterpret_cast<const float4*>(cbb + xb + d * 512 + 256);
                const float4 a0 = *reinterpret_cast<const float4*>(zb + xa + d * 1024 + 0);
                const float4 a1 = *reinterpret_cast<const float4*>(zb + xa + d * 1024 + 256);
                const float4 a2 = *reinterpret_cast<const float4*>(zb + xa + d * 1024 + 512);
                const float4 a3 = *reinterpret_cast<const float4*>(zb + xa + d * 1024 + 768);
#define FMAS(R, AV)                                                           \
                acc[R][0] = fmaf(AV, q0.x, acc[R][0]);                        \
                acc[R][1] = fmaf(AV, q0.y, acc[R][1]);                        \
                acc[R][2] = fmaf(AV, q0.z, acc[R][2]);                        \
                acc[R][3] = fmaf(AV, q0.w, acc[R][3]);                        \
                acc[R][4] = fmaf(AV, q1.x, acc[R][4]);                        \
                acc[R][5] = fmaf(AV, q1.y, acc[R][5]);                        \
                acc[R][6] = fmaf(AV, q1.z, acc[R][6]);                        \
                acc[R][7] = fmaf(AV, q1.w, acc[R][7]);
                FMAS(0,  a0.x) FMAS(1,  a0.y) FMAS(2,  a0.z) FMAS(3,  a0.w)
                FMAS(4,  a1.x) FMAS(5,  a1.y) FMAS(6,  a1.z) FMAS(7,  a1.w)
                FMAS(8,  a2.x) FMAS(9,  a2.y) FMAS(10, a2.z) FMAS(11, a2.w)
                FMAS(12, a3.x) FMAS(13, a3.y) FMAS(14, a3.z) FMAS(15, a3.w)
#undef FMAS
            }
        }
    }

    // ---- Epilogue: d2 + per-row argmin over this block's 128 cols ----
    float zq[16], cq[8];
#pragma unroll
    for (int j = 0; j < 16; ++j) zq[j] = z_sq[b0 + tr * 16 + j];
#pragma unroll
    for (int j = 0; j < 8; ++j) cq[j] = c_sq[k0 + c0l + j];

    float mv[16];
    int   mi[16];
#pragma unroll
    for (int r = 0; r < 16; ++r) {
        mv[r] = FLT_MAX; mi[r] = 0;
#pragma unroll
        for (int c = 0; c < 8; ++c) {
            float s = fmaf(-2.f, acc[r][c], zq[r]) + cq[c];
            if (s < mv[r]) { mv[r] = s; mi[r] = k0 + c0l + c; }
        }
        // merge across the 4 col-groups of this wave
#pragma unroll
        for (int off = 16; off <= 32; off <<= 1) {
            float v2 = __shfl_xor(mv[r], off);
            int   i2 = __shfl_xor(mi[r], off);
            if (v2 < mv[r] || (v2 == mv[r] && i2 < mi[r])) { mv[r] = v2; mi[r] = i2; }
        }
    }

    __syncthreads();   // compute readers done before aliasing sm
    float (*mbuf)[256][2] = reinterpret_cast<float (*)[256][2]>(&sm[0]);
    if (cg == 0) {
#pragma unroll
        for (int r = 0; r < 16; ++r) {
            mbuf[wid][tr * 16 + r][0] = mv[r];
            mbuf[wid][tr * 16 + r][1] = (float)mi[r];
        }
    }
    __syncthreads();
    // merge the 4 waves (ascending wid = ascending col -> first-min semantics)
    {
        float v = mbuf[0][tid][0];
        int   idx = (int)mbuf[0][tid][1];
#pragma unroll
        for (int w = 1; w < 4; ++w) {
            float v2 = mbuf[w][tid][0];
            int   i2 = (int)mbuf[w][tid][1];
            if (v2 < v || (v2 == v && i2 < idx)) { v = v2; idx = i2; }
        }
        partials[(size_t)(b0 + tid) * 64 + cb] = make_float2(v, (float)idx);
    }
}

// ---------------------------------------------------------------------------
// Kernel 1b: reduce 64 col-block partials per row -> final index.
// ---------------------------------------------------------------------------
__global__ __launch_bounds__(256)
void reduce_kernel(const float2* __restrict__ partials,
                   float* __restrict__ out_idx_f) {
    const int row  = blockIdx.x * 4 + (threadIdx.x >> 6);
    const int lane = threadIdx.x & 63;
    float2 p = partials[(size_t)row * 64 + lane];
    float v = p.x;
    int idx = (int)p.y;
#pragma unroll
    for (int off = 32; off >= 1; off >>= 1) {
        float v2 = __shfl_xor(v, off);
        int   i2 = __shfl_xor(idx, off);
        if (v2 < v || (v2 == v && i2 < idx)) { v = v2; idx = i2; }
    }
    if (lane == 0) out_idx_f[row] = (float)idx;
}

// ---------------------------------------------------------------------------
// Kernel 2: gather z_q + scatter EMA contributions into the outputs.
// ---------------------------------------------------------------------------
__global__ __launch_bounds__(256)
void scatter_kernel(const float* __restrict__ z_e,
                    const float* __restrict__ codebook,
                    const float* __restrict__ out_idx_f,
                    float* __restrict__ z_q,
                    float* __restrict__ o_ncs,
                    float* __restrict__ o_nemcb)
{
    const int wave = threadIdx.x >> 6;
    const int lane = threadIdx.x & 63;
    const int b = blockIdx.x * 4 + wave;
    const int idx = (int)out_idx_f[b];
#pragma unroll
    for (int i = 0; i < 2; ++i) {
        int d = i * 256 + lane * 4;
        float4 cq = *reinterpret_cast<const float4*>(
            codebook + (size_t)idx * D_SZ + d);
        *reinterpret_cast<float4*>(z_q + (size_t)b * D_SZ + d) = cq;
        float4 zv = *reinterpret_cast<const float4*>(
            z_e + (size_t)b * D_SZ + d);
        atomicAdd(o_nemcb + (size_t)idx * D_SZ + d + 0, OMD * zv.x);
        atomicAdd(o_nemcb + (size_t)idx * D_SZ + d + 1, OMD * zv.y);
        atomicAdd(o_nemcb + (size_t)idx * D_SZ + d + 2, OMD * zv.z);
        atomicAdd(o_nemcb + (size_t)idx * D_SZ + d + 3, OMD * zv.w);
    }
    if (lane == 0) atomicAdd(o_ncs + idx, OMD);
}

// ---------------------------------------------------------------------------
// Kernel 3: new_codebook = new_ema_codebook / (new_cluster_size + EPS).
// ---------------------------------------------------------------------------
__global__ __launch_bounds__(256)
void finalize_kernel(const float* __restrict__ o_nemcb,
                     const float* __restrict__ o_ncs,
                     float* __restrict__ o_ncb)
{
    const size_t i = (size_t)blockIdx.x * 256 + threadIdx.x;  // float4 index
    const int k = (int)(i >> 7);
    float4 nem = *reinterpret_cast<const float4*>(o_nemcb + i * 4);
    float den = o_ncs[k] + EPS;
    float4 ncb;
    ncb.x = nem.x / den; ncb.y = nem.y / den;
    ncb.z = nem.z / den; ncb.w = nem.w / den;
    *reinterpret_cast<float4*>(o_ncb + i * 4) = ncb;
}

// ---------------------------------------------------------------------------
extern "C" void kernel_launch(void* const* d_in, const int* in_sizes, int n_in,
                              void* d_out, int out_size, void* d_ws, size_t ws_size,
                              hipStream_t stream) {
    const float* z_e      = (const float*)d_in[0];   // (B, D)
    const float* codebook = (const float*)d_in[1];   // (K, D)
    const float* ema_cs   = (const float*)d_in[2];   // (K,)
    const float* ema_cb   = (const float*)d_in[3];   // (K, D)

    float* out = (float*)d_out;
    float* o_zq    = out;                                  // B*D
    float* o_idx   = out + (size_t)B_SZ * D_SZ;            // B
    float* o_ncb   = o_idx + B_SZ;                         // K*D
    float* o_ncs   = o_ncb + (size_t)K_SZ * D_SZ;          // K
    float* o_nemcb = o_ncs + K_SZ;                         // K*D

    // Scratch parked inside o_zq (overwritten by scatter_kernel afterwards).
    float2* w_part = (float2*)o_zq;
    float*  w_csq  = o_zq + (size_t)B_SZ * 64 * 2;
    float*  w_zsq  = w_csq + K_SZ;

    rowsq_kernel<<<K_SZ / 4, 256, 0, stream>>>(codebook, w_csq);
    rowsq_kernel<<<B_SZ / 4, 256, 0, stream>>>(z_e, w_zsq);
    init_ema_kernel<<<K_SZ * D_SZ / 4 / 256, 256, 0, stream>>>(
        ema_cb, ema_cs, o_nemcb, o_ncs);
    argmin_kernel<<<(B_SZ / 256) * (K_SZ / 128), 256, 0, stream>>>(
        z_e, codebook, w_csq, w_zsq, w_part);
    reduce_kernel<<<B_SZ / 4, 256, 0, stream>>>(w_part, o_idx);
    scatter_kernel<<<B_SZ / 4, 256, 0, stream>>>(z_e, codebook, o_idx,
                                                 o_zq, o_ncs, o_nemcb);
    finalize_kernel<<<K_SZ * D_SZ / 4 / 256, 256, 0, stream>>>(
        o_nemcb, o_ncs, o_ncb);
}

// Round 7
// 2376.667 us; speedup vs baseline: 11.0777x; 1.4678x over previous
//
#include <hip/hip_runtime.h>
#include <cfloat>

// Problem constants
#define B_SZ 32768
#define K_SZ 8192
#define D_SZ 512

static constexpr float DECAY = 0.99f;
static constexpr float OMD   = 1.0f - 0.99f;
static constexpr float EPS   = 1e-5f;

typedef __attribute__((ext_vector_type(8))) __bf16 bf16x8;
typedef __attribute__((ext_vector_type(4))) float  f32x4;

// ---------------------------------------------------------------------------
// Scratch layout.
// o_zq region (B*D = 16,777,216 floats; all overwritten by scatter at end):
//   [0, 8388608)          z_bf   (B*D bf16 = 33.5 MB)
//   [8388608, 10485760)   cb_bf  (K*D bf16)
//   [10485760, 14680064)  partials float[B][128]  (per-row per-64col-group min)
// o_ncb region (K*D = 4,194,304 floats; written only by finalize at the end):
//   [0, 8192)       c_sq
//   [8192, 40960)   z_sq
//   [40960]         maxcsq
//   [40961]         wl_count (int)
//   [40964, 106500) slots: B x u64 (score_bits<<32 | idx), atomicMin merged
//   [106512, 2106512) worklist (int entries: row*128 + g), cap 2,000,000
// ---------------------------------------------------------------------------
#define ZQF_ZBF    0
#define ZQF_CBBF   8388608
#define ZQF_PART   10485760
#define NCF_CSQ    0
#define NCF_ZSQ    8192
#define NCF_MAXC   40960
#define NCF_WLCNT  40961
#define NCF_SLOTS  40964
#define NCF_WL     106512
#define WL_CAP     2000000

// ---------------------------------------------------------------------------
// Kernel A: row sum-of-squares. One wave per row (D=512).
// ---------------------------------------------------------------------------
__global__ __launch_bounds__(256)
void rowsq_kernel(const float* __restrict__ src, float* __restrict__ dst) {
    const int wave = threadIdx.x >> 6;
    const int lane = threadIdx.x & 63;
    const int r = blockIdx.x * 4 + wave;
    const float* row = src + (size_t)r * D_SZ;
    float s = 0.f;
#pragma unroll
    for (int i = 0; i < 2; ++i) {
        float4 v = *reinterpret_cast<const float4*>(row + i * 256 + lane * 4);
        s += v.x * v.x + v.y * v.y + v.z * v.z + v.w * v.w;
    }
#pragma unroll
    for (int off = 32; off >= 1; off >>= 1) s += __shfl_xor(s, off);
    if (lane == 0) dst[r] = s;
}

// ---------------------------------------------------------------------------
// maxinit: maxcsq = max(c_sq); wl_count = 0.  One block.
// ---------------------------------------------------------------------------
__global__ __launch_bounds__(256)
void maxinit_kernel(const float* __restrict__ c_sq, float* __restrict__ maxcsq,
                    int* __restrict__ wl_count) {
    __shared__ float sm[4];
    float m = 0.f;
    for (int i = threadIdx.x; i < K_SZ; i += 256) m = fmaxf(m, c_sq[i]);
#pragma unroll
    for (int off = 32; off >= 1; off >>= 1) m = fmaxf(m, __shfl_xor(m, off));
    if ((threadIdx.x & 63) == 0) sm[threadIdx.x >> 6] = m;
    __syncthreads();
    if (threadIdx.x == 0) {
        maxcsq[0] = fmaxf(fmaxf(sm[0], sm[1]), fmaxf(sm[2], sm[3]));
        wl_count[0] = 0;
    }
}

// ---------------------------------------------------------------------------
// cvt: fp32 -> bf16 bits (RNE).  8 elems/thread.
// ---------------------------------------------------------------------------
__device__ __forceinline__ unsigned f2bf(float f) {
    unsigned u = __float_as_uint(f);
    return (u + 0x7FFFu + ((u >> 16) & 1u)) >> 16;
}
__global__ __launch_bounds__(256)
void cvt_kernel(const float* __restrict__ src, unsigned short* __restrict__ dst) {
    const size_t i = ((size_t)blockIdx.x * 256 + threadIdx.x) * 8;
    float4 a = *reinterpret_cast<const float4*>(src + i);
    float4 b = *reinterpret_cast<const float4*>(src + i + 4);
    uint4 o;
    o.x = f2bf(a.x) | (f2bf(a.y) << 16);
    o.y = f2bf(a.z) | (f2bf(a.w) << 16);
    o.z = f2bf(b.x) | (f2bf(b.y) << 16);
    o.w = f2bf(b.z) | (f2bf(b.w) << 16);
    *reinterpret_cast<uint4*>(dst + i) = o;
}

// ---------------------------------------------------------------------------
// Kernel B: EMA init. o_nemcb = DECAY*ema_cb; o_ncs = DECAY*ema_cs.
// ---------------------------------------------------------------------------
__global__ __launch_bounds__(256)
void init_ema_kernel(const float* __restrict__ ema_cb,
                     const float* __restrict__ ema_cs,
                     float* __restrict__ o_nemcb,
                     float* __restrict__ o_ncs) {
    const size_t i = (size_t)blockIdx.x * 256 + threadIdx.x;
    float4 e = *reinterpret_cast<const float4*>(ema_cb + i * 4);
    e.x *= DECAY; e.y *= DECAY; e.z *= DECAY; e.w *= DECAY;
    *reinterpret_cast<float4*>(o_nemcb + i * 4) = e;
    if (i < K_SZ) o_ncs[i] = DECAY * ema_cs[i];
}

// ---------------------------------------------------------------------------
// gemm_approx: bf16 MFMA 16x16x32, 128x128 tile, 4 waves (2x2 of 64x64).
// Approx score s_hat = c_sq[col] - 2*dot(z_bf,cb_bf).  Epilogue: per-row min
// over each 64-col wave-span -> partials[row][cb*2 + wc].
// LDS: A,B tiles 128 rows x 32 bf16, row stride 80 B (pad) -> b128 frag
// reads spread evenly over all 8 bank-quads (BW floor, no conflicts).
// Single-buffer 2-barrier K-loop (R5 skeleton: short staging live ranges).
// Fragment maps (gfx950): A/B lane: row|col = l&15, k = (l>>4)*8+j;
// D: row=(l>>4)*4+reg, col=l&15 [m89-verified].
// ---------------------------------------------------------------------------
__global__ __launch_bounds__(256, 3)
void gemm_approx(const unsigned short* __restrict__ zbf,
                 const unsigned short* __restrict__ cbbf,
                 const float* __restrict__ c_sq,
                 float* __restrict__ partials)
{
    __shared__ char lds[20480];          // A: [0,10240), B: [10240,20480)

    const int tid  = threadIdx.x;
    const int lane = tid & 63;
    const int wid  = tid >> 6;
    const int wr   = wid >> 1;           // wave row half (0/1)
    const int wc   = wid & 1;            // wave col half (0/1)
    const int rb   = blockIdx.x >> 6;    // 0..255
    const int cb   = blockIdx.x & 63;    // 0..63
    const int b0   = rb * 128;
    const int k0   = cb * 128;

    f32x4 acc[4][4];
#pragma unroll
    for (int m = 0; m < 4; ++m)
#pragma unroll
        for (int n = 0; n < 4; ++n) acc[m][n] = 0.f;

    // staging: thread -> (row = tid>>1, half = tid&1): 16 bf16 = 32 B
    const int srow  = tid >> 1;
    const int shalf = tid & 1;
    const unsigned short* gz = zbf  + (size_t)(b0 + srow) * 512 + shalf * 16;
    const unsigned short* gc = cbbf + (size_t)(k0 + srow) * 512 + shalf * 16;
    char* wA = lds +         srow * 80 + shalf * 32;
    char* wB = lds + 10240 + srow * 80 + shalf * 32;
    const int fro = (lane & 15) * 80 + (lane >> 4) * 16;   // frag read offset

#pragma unroll 1
    for (int kk = 0; kk < 16; ++kk) {
        uint4 vz0 = *reinterpret_cast<const uint4*>(gz + kk * 32);
        uint4 vz1 = *reinterpret_cast<const uint4*>(gz + kk * 32 + 8);
        uint4 vc0 = *reinterpret_cast<const uint4*>(gc + kk * 32);
        uint4 vc1 = *reinterpret_cast<const uint4*>(gc + kk * 32 + 8);
        __syncthreads();                 // prev chunk's readers done
        *reinterpret_cast<uint4*>(wA)      = vz0;
        *reinterpret_cast<uint4*>(wA + 16) = vz1;
        *reinterpret_cast<uint4*>(wB)      = vc0;
        *reinterpret_cast<uint4*>(wB + 16) = vc1;
        __syncthreads();

        bf16x8 af[4], bfr[4];
#pragma unroll
        for (int m = 0; m < 4; ++m)
            af[m] = *reinterpret_cast<const bf16x8*>(
                lds + (wr * 64 + m * 16) * 80 + fro);
#pragma unroll
        for (int n = 0; n < 4; ++n)
            bfr[n] = *reinterpret_cast<const bf16x8*>(
                lds + 10240 + (wc * 64 + n * 16) * 80 + fro);
#pragma unroll
        for (int m = 0; m < 4; ++m)
#pragma unroll
            for (int n = 0; n < 4; ++n)
                acc[m][n] = __builtin_amdgcn_mfma_f32_16x16x32_bf16(
                    af[m], bfr[n], acc[m][n], 0, 0, 0);
    }

    // ---- epilogue: s_hat = c_sq - 2*dot; per-row min over this wave's 64 cols
    float csq[4];
#pragma unroll
    for (int n = 0; n < 4; ++n)
        csq[n] = c_sq[k0 + wc * 64 + n * 16 + (lane & 15)];

    float mn[16];
#pragma unroll
    for (int m = 0; m < 4; ++m) {
#pragma unroll
        for (int r = 0; r < 4; ++r) {
            float v = fmaf(-2.f, acc[m][0][r], csq[0]);
            v = fminf(v, fmaf(-2.f, acc[m][1][r], csq[1]));
            v = fminf(v, fmaf(-2.f, acc[m][2][r], csq[2]));
            v = fminf(v, fmaf(-2.f, acc[m][3][r], csq[3]));
#pragma unroll
            for (int off = 1; off <= 8; off <<= 1)
                v = fminf(v, __shfl_xor(v, off));   // across lane&15 group
            mn[m * 4 + r] = v;
        }
    }
    if ((lane & 15) == 0) {
#pragma unroll
        for (int m = 0; m < 4; ++m)
#pragma unroll
            for (int r = 0; r < 4; ++r)
                partials[(size_t)(b0 + wr * 64 + m * 16 + (lane >> 4) * 4 + r) * 128
                         + cb * 2 + wc] = mn[m * 4 + r];
    }
}

// ---------------------------------------------------------------------------
// reduce2: per row, m_hat = min over 128 subgroup-mins; flag subgroups with
// min <= m_hat + THR into worklist; init result slot.
// THR = 2B (rigorous bf16-RNE error bound 2^-7*||z||*||c|| per score, x2 for
// min-vs-min comparison) * 1.4 slack + 0.3 abs.
// ---------------------------------------------------------------------------
__global__ __launch_bounds__(256)
void reduce2_kernel(const float* __restrict__ partials,
                    const float* __restrict__ z_sq,
                    const float* __restrict__ maxcsq,
                    int* __restrict__ wl_count, int* __restrict__ wl,
                    unsigned long long* __restrict__ slots)
{
    const int row  = blockIdx.x * 4 + (threadIdx.x >> 6);
    const int lane = threadIdx.x & 63;
    const float p0 = partials[(size_t)row * 128 + lane];
    const float p1 = partials[(size_t)row * 128 + 64 + lane];
    float m = fminf(p0, p1);
#pragma unroll
    for (int off = 1; off <= 32; off <<= 1) m = fminf(m, __shfl_xor(m, off));
    const float thr = 0.0225f * sqrtf(z_sq[row] * maxcsq[0]) + 0.3f;
    const float lim = m + thr;
    if (lane == 0) slots[row] = 0xFFFFFFFFFFFFFFFFull;
    if (p0 <= lim) {
        int pos = atomicAdd(wl_count, 1);
        if (pos < WL_CAP) wl[pos] = row * 128 + lane;
    }
    if (p1 <= lim) {
        int pos = atomicAdd(wl_count, 1);
        if (pos < WL_CAP) wl[pos] = row * 128 + 64 + lane;
    }
}

// ---------------------------------------------------------------------------
// rescore: exact fp32 scores for flagged 64-col subgroups; same arithmetic
// chain as the R2 kernel (sequential d ascending, fmaf(z,c,acc); then
// s = fmaf(-2,acc,z_sq)+c_sq; first-min tie-break) -> identical final index.
// One wave per worklist entry (grid-stride). LDS staged, coalesced.
// ---------------------------------------------------------------------------
__global__ __launch_bounds__(256, 2)
void rescore_kernel(const float* __restrict__ z_e,
                    const float* __restrict__ codebook,
                    const float* __restrict__ c_sq,
                    const float* __restrict__ z_sq,
                    const int* __restrict__ wl_count,
                    const int* __restrict__ wl,
                    unsigned long long* __restrict__ slots)
{
    __shared__ float zl[4][512];
    __shared__ float cl[4][32][65];      // [wave][d][col], col-pad 65
    const int tid = threadIdx.x, wid = tid >> 6, lane = tid & 63;
    const int nwaves = gridDim.x * 4;
    const int wgid = blockIdx.x * 4 + wid;
    const int total = wl_count[0];

    for (int i = wgid; i < total; i += nwaves) {
        const int e = wl[i];
        const int row = e >> 7;
        const int g = e & 127;
        const int kb = g * 64;
        // stage z row (exact fp32)
        {
            float4 a = *reinterpret_cast<const float4*>(z_e + (size_t)row * 512 + lane * 8);
            float4 b = *reinterpret_cast<const float4*>(z_e + (size_t)row * 512 + lane * 8 + 4);
            *reinterpret_cast<float4*>(&zl[wid][lane * 8])     = a;
            *reinterpret_cast<float4*>(&zl[wid][lane * 8 + 4]) = b;
        }
        float acc = 0.f;
        for (int dc = 0; dc < 16; ++dc) {
            // stage 64 codebook rows x 32 d, transposed
#pragma unroll
            for (int rg = 0; rg < 8; ++rg) {
                const int rr  = rg * 8 + (lane >> 3);
                const int dd0 = (lane & 7) * 4;
                float4 v = *reinterpret_cast<const float4*>(
                    codebook + (size_t)(kb + rr) * 512 + dc * 32 + dd0);
                cl[wid][dd0 + 0][rr] = v.x;
                cl[wid][dd0 + 1][rr] = v.y;
                cl[wid][dd0 + 2][rr] = v.z;
                cl[wid][dd0 + 3][rr] = v.w;
            }
#pragma unroll 8
            for (int dd = 0; dd < 32; ++dd)
                acc = fmaf(zl[wid][dc * 32 + dd], cl[wid][dd][lane], acc);
        }
        float v = fmaf(-2.f, acc, z_sq[row]) + c_sq[kb + lane];
        int idx = kb + lane;
#pragma unroll
        for (int off = 1; off <= 32; off <<= 1) {
            float v2 = __shfl_xor(v, off);
            int   i2 = __shfl_xor(idx, off);
            if (v2 < v || (v2 == v && i2 < idx)) { v = v2; idx = i2; }
        }
        if (lane == 0)
            atomicMin(slots + row,
                      ((unsigned long long)__float_as_uint(v) << 32) | (unsigned)idx);
    }
}

// ---------------------------------------------------------------------------
// scatter: gather z_q + EMA atomics + write o_idx (reads idx from slots).
// ---------------------------------------------------------------------------
__global__ __launch_bounds__(256)
void scatter_kernel(const float* __restrict__ z_e,
                    const float* __restrict__ codebook,
                    const unsigned long long* __restrict__ slots,
                    float* __restrict__ z_q,
                    float* __restrict__ o_idx,
                    float* __restrict__ o_ncs,
                    float* __restrict__ o_nemcb)
{
    const int wave = threadIdx.x >> 6;
    const int lane = threadIdx.x & 63;
    const int b = blockIdx.x * 4 + wave;
    const int idx = (int)(unsigned)(slots[b] & 0xFFFFFFFFull);
#pragma unroll
    for (int i = 0; i < 2; ++i) {
        int d = i * 256 + lane * 4;
        float4 cq = *reinterpret_cast<const float4*>(
            codebook + (size_t)idx * D_SZ + d);
        *reinterpret_cast<float4*>(z_q + (size_t)b * D_SZ + d) = cq;
        float4 zv = *reinterpret_cast<const float4*>(
            z_e + (size_t)b * D_SZ + d);
        atomicAdd(o_nemcb + (size_t)idx * D_SZ + d + 0, OMD * zv.x);
        atomicAdd(o_nemcb + (size_t)idx * D_SZ + d + 1, OMD * zv.y);
        atomicAdd(o_nemcb + (size_t)idx * D_SZ + d + 2, OMD * zv.z);
        atomicAdd(o_nemcb + (size_t)idx * D_SZ + d + 3, OMD * zv.w);
    }
    if (lane == 0) {
        atomicAdd(o_ncs + idx, OMD);
        o_idx[b] = (float)idx;
    }
}

// ---------------------------------------------------------------------------
// finalize: new_codebook = new_ema_codebook / (new_cluster_size + EPS).
// ---------------------------------------------------------------------------
__global__ __launch_bounds__(256)
void finalize_kernel(const float* __restrict__ o_nemcb,
                     const float* __restrict__ o_ncs,
                     float* __restrict__ o_ncb)
{
    const size_t i = (size_t)blockIdx.x * 256 + threadIdx.x;
    const int k = (int)(i >> 7);
    float4 nem = *reinterpret_cast<const float4*>(o_nemcb + i * 4);
    float den = o_ncs[k] + EPS;
    float4 ncb;
    ncb.x = nem.x / den; ncb.y = nem.y / den;
    ncb.z = nem.z / den; ncb.w = nem.w / den;
    *reinterpret_cast<float4*>(o_ncb + i * 4) = ncb;
}

// ---------------------------------------------------------------------------
extern "C" void kernel_launch(void* const* d_in, const int* in_sizes, int n_in,
                              void* d_out, int out_size, void* d_ws, size_t ws_size,
                              hipStream_t stream) {
    const float* z_e      = (const float*)d_in[0];   // (B, D)
    const float* codebook = (const float*)d_in[1];   // (K, D)
    const float* ema_cs   = (const float*)d_in[2];   // (K,)
    const float* ema_cb   = (const float*)d_in[3];   // (K, D)

    float* out = (float*)d_out;
    float* o_zq    = out;                                  // B*D
    float* o_idx   = out + (size_t)B_SZ * D_SZ;            // B
    float* o_ncb   = o_idx + B_SZ;                         // K*D
    float* o_ncs   = o_ncb + (size_t)K_SZ * D_SZ;          // K
    float* o_nemcb = o_ncs + K_SZ;                         // K*D

    // scratch views
    unsigned short* w_zbf  = (unsigned short*)(o_zq + ZQF_ZBF);
    unsigned short* w_cbbf = (unsigned short*)(o_zq + ZQF_CBBF);
    float*          w_part = o_zq + ZQF_PART;
    float*          w_csq  = o_ncb + NCF_CSQ;
    float*          w_zsq  = o_ncb + NCF_ZSQ;
    float*          w_maxc = o_ncb + NCF_MAXC;
    int*            w_cnt  = (int*)(o_ncb + NCF_WLCNT);
    unsigned long long* w_slots = (unsigned long long*)(o_ncb + NCF_SLOTS);
    int*            w_wl   = (int*)(o_ncb + NCF_WL);

    rowsq_kernel<<<K_SZ / 4, 256, 0, stream>>>(codebook, w_csq);
    rowsq_kernel<<<B_SZ / 4, 256, 0, stream>>>(z_e, w_zsq);
    maxinit_kernel<<<1, 256, 0, stream>>>(w_csq, w_maxc, w_cnt);
    cvt_kernel<<<(int)((size_t)B_SZ * D_SZ / 2048), 256, 0, stream>>>(z_e, w_zbf);
    cvt_kernel<<<(int)((size_t)K_SZ * D_SZ / 2048), 256, 0, stream>>>(codebook, w_cbbf);
    init_ema_kernel<<<K_SZ * D_SZ / 4 / 256, 256, 0, stream>>>(
        ema_cb, ema_cs, o_nemcb, o_ncs);
    gemm_approx<<<(B_SZ / 128) * (K_SZ / 128), 256, 0, stream>>>(
        w_zbf, w_cbbf, w_csq, w_part);
    reduce2_kernel<<<B_SZ / 4, 256, 0, stream>>>(
        w_part, w_zsq, w_maxc, w_cnt, w_wl, w_slots);
    rescore_kernel<<<1024, 256, 0, stream>>>(
        z_e, codebook, w_csq, w_zsq, w_cnt, w_wl, w_slots);
    scatter_kernel<<<B_SZ / 4, 256, 0, stream>>>(
        z_e, codebook, w_slots, o_zq, o_idx, o_ncs, o_nemcb);
    finalize_kernel<<<K_SZ * D_SZ / 4 / 256, 256, 0, stream>>>(
        o_nemcb, o_ncs, o_ncb);
}

// Round 8
// 1736.284 us; speedup vs baseline: 15.1634x; 1.3688x over previous
//
#include <hip/hip_runtime.h>
#include <cfloat>

// Problem constants
#define B_SZ 32768
#define K_SZ 8192
#define D_SZ 512

static constexpr float DECAY = 0.99f;
static constexpr float OMD   = 1.0f - 0.99f;
static constexpr float EPS   = 1e-5f;

typedef __attribute__((ext_vector_type(8))) __bf16 bf16x8;
typedef __attribute__((ext_vector_type(4))) float  f32x4;

// ---------------------------------------------------------------------------
// Scratch layout.
// o_zq region (B*D = 16,777,216 floats; all overwritten by scatter at end):
//   [0, 8388608)          z_bf   (B*D bf16 = 33.5 MB)
//   [8388608, 10485760)   cb_bf  (K*D bf16)
//   [10485760, 14680064)  partials float[B][128]  (per-row per-64col-group min)
// o_ncb region (K*D = 4,194,304 floats; written only by finalize at the end):
//   [0, 8192)        c_sq
//   [8192, 40960)    z_sq
//   [40960]          maxcsq
//   [40961]          wl_count (int)
//   [40964, 41092)   gcnt[128]  (per-subgroup flag counts)
//   [41092, 41220)   cursor[128] (bucket write cursors = exclusive scan)
//   [41220, 106756)  slots: B x u64 (score_bits<<32 | idx), atomicMin merged
//   [106756, ...)    worklist (g-bucketed int entries row*128+g), cap 4e6
// ---------------------------------------------------------------------------
#define ZQF_ZBF    0
#define ZQF_CBBF   8388608
#define ZQF_PART   10485760
#define NCF_CSQ    0
#define NCF_ZSQ    8192
#define NCF_MAXC   40960
#define NCF_WLCNT  40961
#define NCF_GCNT   40964
#define NCF_CUR    41092
#define NCF_SLOTS  41220
#define NCF_WL     106756
#define WL_CAP     4000000

// ---------------------------------------------------------------------------
// Kernel A: row sum-of-squares. One wave per row (D=512).
// ---------------------------------------------------------------------------
__global__ __launch_bounds__(256)
void rowsq_kernel(const float* __restrict__ src, float* __restrict__ dst) {
    const int wave = threadIdx.x >> 6;
    const int lane = threadIdx.x & 63;
    const int r = blockIdx.x * 4 + wave;
    const float* row = src + (size_t)r * D_SZ;
    float s = 0.f;
#pragma unroll
    for (int i = 0; i < 2; ++i) {
        float4 v = *reinterpret_cast<const float4*>(row + i * 256 + lane * 4);
        s += v.x * v.x + v.y * v.y + v.z * v.z + v.w * v.w;
    }
#pragma unroll
    for (int off = 32; off >= 1; off >>= 1) s += __shfl_xor(s, off);
    if (lane == 0) dst[r] = s;
}

// ---------------------------------------------------------------------------
// maxinit: maxcsq = max(c_sq); wl_count = 0; gcnt[] = 0.  One block.
// ---------------------------------------------------------------------------
__global__ __launch_bounds__(256)
void maxinit_kernel(const float* __restrict__ c_sq, float* __restrict__ maxcsq,
                    int* __restrict__ wl_count, int* __restrict__ gcnt) {
    __shared__ float sm[4];
    float m = 0.f;
    for (int i = threadIdx.x; i < K_SZ; i += 256) m = fmaxf(m, c_sq[i]);
#pragma unroll
    for (int off = 32; off >= 1; off >>= 1) m = fmaxf(m, __shfl_xor(m, off));
    if ((threadIdx.x & 63) == 0) sm[threadIdx.x >> 6] = m;
    __syncthreads();
    if (threadIdx.x < 128) gcnt[threadIdx.x] = 0;
    if (threadIdx.x == 0) {
        maxcsq[0] = fmaxf(fmaxf(sm[0], sm[1]), fmaxf(sm[2], sm[3]));
        wl_count[0] = 0;
    }
}

// ---------------------------------------------------------------------------
// cvt: fp32 -> bf16 bits (RNE).  8 elems/thread.
// ---------------------------------------------------------------------------
__device__ __forceinline__ unsigned f2bf(float f) {
    unsigned u = __float_as_uint(f);
    return (u + 0x7FFFu + ((u >> 16) & 1u)) >> 16;
}
__global__ __launch_bounds__(256)
void cvt_kernel(const float* __restrict__ src, unsigned short* __restrict__ dst) {
    const size_t i = ((size_t)blockIdx.x * 256 + threadIdx.x) * 8;
    float4 a = *reinterpret_cast<const float4*>(src + i);
    float4 b = *reinterpret_cast<const float4*>(src + i + 4);
    uint4 o;
    o.x = f2bf(a.x) | (f2bf(a.y) << 16);
    o.y = f2bf(a.z) | (f2bf(a.w) << 16);
    o.z = f2bf(b.x) | (f2bf(b.y) << 16);
    o.w = f2bf(b.z) | (f2bf(b.w) << 16);
    *reinterpret_cast<uint4*>(dst + i) = o;
}

// ---------------------------------------------------------------------------
// Kernel B: EMA init. o_nemcb = DECAY*ema_cb; o_ncs = DECAY*ema_cs.
// ---------------------------------------------------------------------------
__global__ __launch_bounds__(256)
void init_ema_kernel(const float* __restrict__ ema_cb,
                     const float* __restrict__ ema_cs,
                     float* __restrict__ o_nemcb,
                     float* __restrict__ o_ncs) {
    const size_t i = (size_t)blockIdx.x * 256 + threadIdx.x;
    float4 e = *reinterpret_cast<const float4*>(ema_cb + i * 4);
    e.x *= DECAY; e.y *= DECAY; e.z *= DECAY; e.w *= DECAY;
    *reinterpret_cast<float4*>(o_nemcb + i * 4) = e;
    if (i < K_SZ) o_ncs[i] = DECAY * ema_cs[i];
}

// ---------------------------------------------------------------------------
// gemm_approx: bf16 MFMA 16x16x32, 128x128 tile, 4 waves (2x2 of 64x64).
// (unchanged from R7 — its counters become visible this round)
// ---------------------------------------------------------------------------
__global__ __launch_bounds__(256, 3)
void gemm_approx(const unsigned short* __restrict__ zbf,
                 const unsigned short* __restrict__ cbbf,
                 const float* __restrict__ c_sq,
                 float* __restrict__ partials)
{
    __shared__ char lds[20480];          // A: [0,10240), B: [10240,20480)

    const int tid  = threadIdx.x;
    const int lane = tid & 63;
    const int wid  = tid >> 6;
    const int wr   = wid >> 1;           // wave row half (0/1)
    const int wc   = wid & 1;            // wave col half (0/1)
    const int rb   = blockIdx.x >> 6;    // 0..255
    const int cb   = blockIdx.x & 63;    // 0..63
    const int b0   = rb * 128;
    const int k0   = cb * 128;

    f32x4 acc[4][4];
#pragma unroll
    for (int m = 0; m < 4; ++m)
#pragma unroll
        for (int n = 0; n < 4; ++n) acc[m][n] = 0.f;

    const int srow  = tid >> 1;
    const int shalf = tid & 1;
    const unsigned short* gz = zbf  + (size_t)(b0 + srow) * 512 + shalf * 16;
    const unsigned short* gc = cbbf + (size_t)(k0 + srow) * 512 + shalf * 16;
    char* wA = lds +         srow * 80 + shalf * 32;
    char* wB = lds + 10240 + srow * 80 + shalf * 32;
    const int fro = (lane & 15) * 80 + (lane >> 4) * 16;   // frag read offset

#pragma unroll 1
    for (int kk = 0; kk < 16; ++kk) {
        uint4 vz0 = *reinterpret_cast<const uint4*>(gz + kk * 32);
        uint4 vz1 = *reinterpret_cast<const uint4*>(gz + kk * 32 + 8);
        uint4 vc0 = *reinterpret_cast<const uint4*>(gc + kk * 32);
        uint4 vc1 = *reinterpret_cast<const uint4*>(gc + kk * 32 + 8);
        __syncthreads();                 // prev chunk's readers done
        *reinterpret_cast<uint4*>(wA)      = vz0;
        *reinterpret_cast<uint4*>(wA + 16) = vz1;
        *reinterpret_cast<uint4*>(wB)      = vc0;
        *reinterpret_cast<uint4*>(wB + 16) = vc1;
        __syncthreads();

        bf16x8 af[4], bfr[4];
#pragma unroll
        for (int m = 0; m < 4; ++m)
            af[m] = *reinterpret_cast<const bf16x8*>(
                lds + (wr * 64 + m * 16) * 80 + fro);
#pragma unroll
        for (int n = 0; n < 4; ++n)
            bfr[n] = *reinterpret_cast<const bf16x8*>(
                lds + 10240 + (wc * 64 + n * 16) * 80 + fro);
#pragma unroll
        for (int m = 0; m < 4; ++m)
#pragma unroll
            for (int n = 0; n < 4; ++n)
                acc[m][n] = __builtin_amdgcn_mfma_f32_16x16x32_bf16(
                    af[m], bfr[n], acc[m][n], 0, 0, 0);
    }

    // ---- epilogue: s_hat = c_sq - 2*dot; per-row min over this wave's 64 cols
    float csq[4];
#pragma unroll
    for (int n = 0; n < 4; ++n)
        csq[n] = c_sq[k0 + wc * 64 + n * 16 + (lane & 15)];

    float mn[16];
#pragma unroll
    for (int m = 0; m < 4; ++m) {
#pragma unroll
        for (int r = 0; r < 4; ++r) {
            float v = fmaf(-2.f, acc[m][0][r], csq[0]);
            v = fminf(v, fmaf(-2.f, acc[m][1][r], csq[1]));
            v = fminf(v, fmaf(-2.f, acc[m][2][r], csq[2]));
            v = fminf(v, fmaf(-2.f, acc[m][3][r], csq[3]));
#pragma unroll
            for (int off = 1; off <= 8; off <<= 1)
                v = fminf(v, __shfl_xor(v, off));   // across lane&15 group
            mn[m * 4 + r] = v;
        }
    }
    if ((lane & 15) == 0) {
#pragma unroll
        for (int m = 0; m < 4; ++m)
#pragma unroll
            for (int r = 0; r < 4; ++r)
                partials[(size_t)(b0 + wr * 64 + m * 16 + (lane >> 4) * 4 + r) * 128
                         + cb * 2 + wc] = mn[m * 4 + r];
    }
}

// ---------------------------------------------------------------------------
// reduce2 (pass A): per row, m_hat = min over 128 subgroup-mins; COUNT
// flagged subgroups per g (atomicAdd gcnt); init result slot.
// THR identical to R7 (passed).
// ---------------------------------------------------------------------------
__global__ __launch_bounds__(256)
void reduce2_kernel(const float* __restrict__ partials,
                    const float* __restrict__ z_sq,
                    const float* __restrict__ maxcsq,
                    int* __restrict__ gcnt,
                    unsigned long long* __restrict__ slots)
{
    const int row  = blockIdx.x * 4 + (threadIdx.x >> 6);
    const int lane = threadIdx.x & 63;
    const float p0 = partials[(size_t)row * 128 + lane];
    const float p1 = partials[(size_t)row * 128 + 64 + lane];
    float m = fminf(p0, p1);
#pragma unroll
    for (int off = 1; off <= 32; off <<= 1) m = fminf(m, __shfl_xor(m, off));
    const float thr = 0.0225f * sqrtf(z_sq[row] * maxcsq[0]) + 0.3f;
    const float lim = m + thr;
    if (lane == 0) slots[row] = 0xFFFFFFFFFFFFFFFFull;
    if (p0 <= lim) atomicAdd(gcnt + lane, 1);
    if (p1 <= lim) atomicAdd(gcnt + 64 + lane, 1);
}

// ---------------------------------------------------------------------------
// scan: exclusive scan of gcnt[128] -> cursor[128]; wl_count = total.
// One thread (128 adds, negligible).
// ---------------------------------------------------------------------------
__global__ void scan_kernel(const int* __restrict__ gcnt,
                            int* __restrict__ cursor,
                            int* __restrict__ wl_count) {
    if (threadIdx.x == 0 && blockIdx.x == 0) {
        int run = 0;
        for (int g = 0; g < 128; ++g) { cursor[g] = run; run += gcnt[g]; }
        wl_count[0] = run;
    }
}

// ---------------------------------------------------------------------------
// place (pass B): recompute flags (deterministic re-run of pass A's logic)
// and write entries bucket-contiguously: wl[cursor[g]++] = row*128 + g.
// Bucketing makes concurrent rescore waves share the same codebook block
// (L2/L3-resident) instead of thrashing L3 with ~4096 distinct 131 KB blocks.
// ---------------------------------------------------------------------------
__global__ __launch_bounds__(256)
void place_kernel(const float* __restrict__ partials,
                  const float* __restrict__ z_sq,
                  const float* __restrict__ maxcsq,
                  int* __restrict__ cursor,
                  int* __restrict__ wl)
{
    const int row  = blockIdx.x * 4 + (threadIdx.x >> 6);
    const int lane = threadIdx.x & 63;
    const float p0 = partials[(size_t)row * 128 + lane];
    const float p1 = partials[(size_t)row * 128 + 64 + lane];
    float m = fminf(p0, p1);
#pragma unroll
    for (int off = 1; off <= 32; off <<= 1) m = fminf(m, __shfl_xor(m, off));
    const float thr = 0.0225f * sqrtf(z_sq[row] * maxcsq[0]) + 0.3f;
    const float lim = m + thr;
    if (p0 <= lim) {
        int pos = atomicAdd(cursor + lane, 1);
        if (pos < WL_CAP) wl[pos] = row * 128 + lane;
    }
    if (p1 <= lim) {
        int pos = atomicAdd(cursor + 64 + lane, 1);
        if (pos < WL_CAP) wl[pos] = row * 128 + 64 + lane;
    }
}

// ---------------------------------------------------------------------------
// rescore: exact fp32 scores for flagged 64-col subgroups (identical
// arithmetic chain to R2/R7 -> identical indices). One wave per entry,
// grid-stride; wl is g-bucketed so concurrent waves share codebook blocks.
// ---------------------------------------------------------------------------
__global__ __launch_bounds__(256, 2)
void rescore_kernel(const float* __restrict__ z_e,
                    const float* __restrict__ codebook,
                    const float* __restrict__ c_sq,
                    const float* __restrict__ z_sq,
                    const int* __restrict__ wl_count,
                    const int* __restrict__ wl,
                    unsigned long long* __restrict__ slots)
{
    __shared__ float zl[4][512];
    __shared__ float cl[4][32][65];      // [wave][d][col], col-pad 65
    const int tid = threadIdx.x, wid = tid >> 6, lane = tid & 63;
    const int nwaves = gridDim.x * 4;
    const int wgid = blockIdx.x * 4 + wid;
    const int total = wl_count[0];

    for (int i = wgid; i < total; i += nwaves) {
        const int e = wl[i];
        const int row = e >> 7;
        const int g = e & 127;
        const int kb = g * 64;
        {
            float4 a = *reinterpret_cast<const float4*>(z_e + (size_t)row * 512 + lane * 8);
            float4 b = *reinterpret_cast<const float4*>(z_e + (size_t)row * 512 + lane * 8 + 4);
            *reinterpret_cast<float4*>(&zl[wid][lane * 8])     = a;
            *reinterpret_cast<float4*>(&zl[wid][lane * 8 + 4]) = b;
        }
        float acc = 0.f;
        for (int dc = 0; dc < 16; ++dc) {
#pragma unroll
            for (int rg = 0; rg < 8; ++rg) {
                const int rr  = rg * 8 + (lane >> 3);
                const int dd0 = (lane & 7) * 4;
                float4 v = *reinterpret_cast<const float4*>(
                    codebook + (size_t)(kb + rr) * 512 + dc * 32 + dd0);
                cl[wid][dd0 + 0][rr] = v.x;
                cl[wid][dd0 + 1][rr] = v.y;
                cl[wid][dd0 + 2][rr] = v.z;
                cl[wid][dd0 + 3][rr] = v.w;
            }
#pragma unroll 8
            for (int dd = 0; dd < 32; ++dd)
                acc = fmaf(zl[wid][dc * 32 + dd], cl[wid][dd][lane], acc);
        }
        float v = fmaf(-2.f, acc, z_sq[row]) + c_sq[kb + lane];
        int idx = kb + lane;
#pragma unroll
        for (int off = 1; off <= 32; off <<= 1) {
            float v2 = __shfl_xor(v, off);
            int   i2 = __shfl_xor(idx, off);
            if (v2 < v || (v2 == v && i2 < idx)) { v = v2; idx = i2; }
        }
        if (lane == 0)
            atomicMin(slots + row,
                      ((unsigned long long)__float_as_uint(v) << 32) | (unsigned)idx);
    }
}

// ---------------------------------------------------------------------------
// scatter: gather z_q + EMA atomics + write o_idx (reads idx from slots).
// ---------------------------------------------------------------------------
__global__ __launch_bounds__(256)
void scatter_kernel(const float* __restrict__ z_e,
                    const float* __restrict__ codebook,
                    const unsigned long long* __restrict__ slots,
                    float* __restrict__ z_q,
                    float* __restrict__ o_idx,
                    float* __restrict__ o_ncs,
                    float* __restrict__ o_nemcb)
{
    const int wave = threadIdx.x >> 6;
    const int lane = threadIdx.x & 63;
    const int b = blockIdx.x * 4 + wave;
    const int idx = (int)(unsigned)(slots[b] & 0xFFFFFFFFull);
#pragma unroll
    for (int i = 0; i < 2; ++i) {
        int d = i * 256 + lane * 4;
        float4 cq = *reinterpret_cast<const float4*>(
            codebook + (size_t)idx * D_SZ + d);
        *reinterpret_cast<float4*>(z_q + (size_t)b * D_SZ + d) = cq;
        float4 zv = *reinterpret_cast<const float4*>(
            z_e + (size_t)b * D_SZ + d);
        atomicAdd(o_nemcb + (size_t)idx * D_SZ + d + 0, OMD * zv.x);
        atomicAdd(o_nemcb + (size_t)idx * D_SZ + d + 1, OMD * zv.y);
        atomicAdd(o_nemcb + (size_t)idx * D_SZ + d + 2, OMD * zv.z);
        atomicAdd(o_nemcb + (size_t)idx * D_SZ + d + 3, OMD * zv.w);
    }
    if (lane == 0) {
        atomicAdd(o_ncs + idx, OMD);
        o_idx[b] = (float)idx;
    }
}

// ---------------------------------------------------------------------------
// finalize: new_codebook = new_ema_codebook / (new_cluster_size + EPS).
// ---------------------------------------------------------------------------
__global__ __launch_bounds__(256)
void finalize_kernel(const float* __restrict__ o_nemcb,
                     const float* __restrict__ o_ncs,
                     float* __restrict__ o_ncb)
{
    const size_t i = (size_t)blockIdx.x * 256 + threadIdx.x;
    const int k = (int)(i >> 7);
    float4 nem = *reinterpret_cast<const float4*>(o_nemcb + i * 4);
    float den = o_ncs[k] + EPS;
    float4 ncb;
    ncb.x = nem.x / den; ncb.y = nem.y / den;
    ncb.z = nem.z / den; ncb.w = nem.w / den;
    *reinterpret_cast<float4*>(o_ncb + i * 4) = ncb;
}

// ---------------------------------------------------------------------------
extern "C" void kernel_launch(void* const* d_in, const int* in_sizes, int n_in,
                              void* d_out, int out_size, void* d_ws, size_t ws_size,
                              hipStream_t stream) {
    const float* z_e      = (const float*)d_in[0];   // (B, D)
    const float* codebook = (const float*)d_in[1];   // (K, D)
    const float* ema_cs   = (const float*)d_in[2];   // (K,)
    const float* ema_cb   = (const float*)d_in[3];   // (K, D)

    float* out = (float*)d_out;
    float* o_zq    = out;                                  // B*D
    float* o_idx   = out + (size_t)B_SZ * D_SZ;            // B
    float* o_ncb   = o_idx + B_SZ;                         // K*D
    float* o_ncs   = o_ncb + (size_t)K_SZ * D_SZ;          // K
    float* o_nemcb = o_ncs + K_SZ;                         // K*D

    // scratch views
    unsigned short* w_zbf  = (unsigned short*)(o_zq + ZQF_ZBF);
    unsigned short* w_cbbf = (unsigned short*)(o_zq + ZQF_CBBF);
    float*          w_part = o_zq + ZQF_PART;
    float*          w_csq  = o_ncb + NCF_CSQ;
    float*          w_zsq  = o_ncb + NCF_ZSQ;
    float*          w_maxc = o_ncb + NCF_MAXC;
    int*            w_cnt  = (int*)(o_ncb + NCF_WLCNT);
    int*            w_gcnt = (int*)(o_ncb + NCF_GCNT);
    int*            w_cur  = (int*)(o_ncb + NCF_CUR);
    unsigned long long* w_slots = (unsigned long long*)(o_ncb + NCF_SLOTS);
    int*            w_wl   = (int*)(o_ncb + NCF_WL);

    rowsq_kernel<<<K_SZ / 4, 256, 0, stream>>>(codebook, w_csq);
    rowsq_kernel<<<B_SZ / 4, 256, 0, stream>>>(z_e, w_zsq);
    maxinit_kernel<<<1, 256, 0, stream>>>(w_csq, w_maxc, w_cnt, w_gcnt);
    cvt_kernel<<<(int)((size_t)B_SZ * D_SZ / 2048), 256, 0, stream>>>(z_e, w_zbf);
    cvt_kernel<<<(int)((size_t)K_SZ * D_SZ / 2048), 256, 0, stream>>>(codebook, w_cbbf);
    init_ema_kernel<<<K_SZ * D_SZ / 4 / 256, 256, 0, stream>>>(
        ema_cb, ema_cs, o_nemcb, o_ncs);
    gemm_approx<<<(B_SZ / 128) * (K_SZ / 128), 256, 0, stream>>>(
        w_zbf, w_cbbf, w_csq, w_part);
    reduce2_kernel<<<B_SZ / 4, 256, 0, stream>>>(
        w_part, w_zsq, w_maxc, w_gcnt, w_slots);
    scan_kernel<<<1, 64, 0, stream>>>(w_gcnt, w_cur, w_cnt);
    place_kernel<<<B_SZ / 4, 256, 0, stream>>>(
        w_part, w_zsq, w_maxc, w_cur, w_wl);
    rescore_kernel<<<1024, 256, 0, stream>>>(
        z_e, codebook, w_csq, w_zsq, w_cnt, w_wl, w_slots);
    scatter_kernel<<<B_SZ / 4, 256, 0, stream>>>(
        z_e, codebook, w_slots, o_zq, o_idx, o_ncs, o_nemcb);
    finalize_kernel<<<K_SZ * D_SZ / 4 / 256, 256, 0, stream>>>(
        o_nemcb, o_ncs, o_ncb);
}

// Round 9
// 1494.853 us; speedup vs baseline: 17.6124x; 1.1615x over previous
//
#include <hip/hip_runtime.h>
#include <cfloat>

// Problem constants
#define B_SZ 32768
#define K_SZ 8192
#define D_SZ 512

static constexpr float DECAY = 0.99f;
static constexpr float OMD   = 1.0f - 0.99f;
static constexpr float EPS   = 1e-5f;

typedef __attribute__((ext_vector_type(8))) __bf16 bf16x8;
typedef __attribute__((ext_vector_type(4))) float  f32x4;

// ---------------------------------------------------------------------------
// Scratch layout.
// o_zq region (B*D = 16,777,216 floats; all overwritten by scatter at end):
//   [0, 8388608)          z_bf (B*D bf16)  -- DEAD after gemm; REUSED as
//                         cbT4 float[128][8192][4] (16 MB) by transpose
//   [8388608, 10485760)   cb_bf  (K*D bf16)
//   [10485760, 14680064)  partials float[B][128]
// o_ncb region (K*D floats; written only by finalize at the end):
//   [0, 8192)        c_sq
//   [8192, 40960)    z_sq
//   [40960]          maxcsq
//   [40961]          wl_count
//   [40964, 41092)   gcnt[128]
//   [41092, 41220)   cursor[128]
//   [41220, 106756)  slots: B x u64
//   [106756, ...)    worklist (g-bucketed), cap 4e6
// ---------------------------------------------------------------------------
#define ZQF_ZBF    0
#define ZQF_CBT    0
#define ZQF_CBBF   8388608
#define ZQF_PART   10485760
#define NCF_CSQ    0
#define NCF_ZSQ    8192
#define NCF_MAXC   40960
#define NCF_WLCNT  40961
#define NCF_GCNT   40964
#define NCF_CUR    41092
#define NCF_SLOTS  41220
#define NCF_WL     106756
#define WL_CAP     4000000

// ---------------------------------------------------------------------------
__global__ __launch_bounds__(256)
void rowsq_kernel(const float* __restrict__ src, float* __restrict__ dst) {
    const int wave = threadIdx.x >> 6;
    const int lane = threadIdx.x & 63;
    const int r = blockIdx.x * 4 + wave;
    const float* row = src + (size_t)r * D_SZ;
    float s = 0.f;
#pragma unroll
    for (int i = 0; i < 2; ++i) {
        float4 v = *reinterpret_cast<const float4*>(row + i * 256 + lane * 4);
        s += v.x * v.x + v.y * v.y + v.z * v.z + v.w * v.w;
    }
#pragma unroll
    for (int off = 32; off >= 1; off >>= 1) s += __shfl_xor(s, off);
    if (lane == 0) dst[r] = s;
}

// ---------------------------------------------------------------------------
__global__ __launch_bounds__(256)
void maxinit_kernel(const float* __restrict__ c_sq, float* __restrict__ maxcsq,
                    int* __restrict__ wl_count, int* __restrict__ gcnt) {
    __shared__ float sm[4];
    float m = 0.f;
    for (int i = threadIdx.x; i < K_SZ; i += 256) m = fmaxf(m, c_sq[i]);
#pragma unroll
    for (int off = 32; off >= 1; off >>= 1) m = fmaxf(m, __shfl_xor(m, off));
    if ((threadIdx.x & 63) == 0) sm[threadIdx.x >> 6] = m;
    __syncthreads();
    if (threadIdx.x < 128) gcnt[threadIdx.x] = 0;
    if (threadIdx.x == 0) {
        maxcsq[0] = fmaxf(fmaxf(sm[0], sm[1]), fmaxf(sm[2], sm[3]));
        wl_count[0] = 0;
    }
}

// ---------------------------------------------------------------------------
__device__ __forceinline__ unsigned f2bf(float f) {
    unsigned u = __float_as_uint(f);
    return (u + 0x7FFFu + ((u >> 16) & 1u)) >> 16;
}
__global__ __launch_bounds__(256)
void cvt_kernel(const float* __restrict__ src, unsigned short* __restrict__ dst) {
    const size_t i = ((size_t)blockIdx.x * 256 + threadIdx.x) * 8;
    float4 a = *reinterpret_cast<const float4*>(src + i);
    float4 b = *reinterpret_cast<const float4*>(src + i + 4);
    uint4 o;
    o.x = f2bf(a.x) | (f2bf(a.y) << 16);
    o.y = f2bf(a.z) | (f2bf(a.w) << 16);
    o.z = f2bf(b.x) | (f2bf(b.y) << 16);
    o.w = f2bf(b.z) | (f2bf(b.w) << 16);
    *reinterpret_cast<uint4*>(dst + i) = o;
}

// ---------------------------------------------------------------------------
__global__ __launch_bounds__(256)
void init_ema_kernel(const float* __restrict__ ema_cb,
                     const float* __restrict__ ema_cs,
                     float* __restrict__ o_nemcb,
                     float* __restrict__ o_ncs) {
    const size_t i = (size_t)blockIdx.x * 256 + threadIdx.x;
    float4 e = *reinterpret_cast<const float4*>(ema_cb + i * 4);
    e.x *= DECAY; e.y *= DECAY; e.z *= DECAY; e.w *= DECAY;
    *reinterpret_cast<float4*>(o_nemcb + i * 4) = e;
    if (i < K_SZ) o_ncs[i] = DECAY * ema_cs[i];
}

// ---------------------------------------------------------------------------
// gemm_approx (unchanged from R7/R8).
// ---------------------------------------------------------------------------
__global__ __launch_bounds__(256, 3)
void gemm_approx(const unsigned short* __restrict__ zbf,
                 const unsigned short* __restrict__ cbbf,
                 const float* __restrict__ c_sq,
                 float* __restrict__ partials)
{
    __shared__ char lds[20480];

    const int tid  = threadIdx.x;
    const int lane = tid & 63;
    const int wid  = tid >> 6;
    const int wr   = wid >> 1;
    const int wc   = wid & 1;
    const int rb   = blockIdx.x >> 6;
    const int cb   = blockIdx.x & 63;
    const int b0   = rb * 128;
    const int k0   = cb * 128;

    f32x4 acc[4][4];
#pragma unroll
    for (int m = 0; m < 4; ++m)
#pragma unroll
        for (int n = 0; n < 4; ++n) acc[m][n] = 0.f;

    const int srow  = tid >> 1;
    const int shalf = tid & 1;
    const unsigned short* gz = zbf  + (size_t)(b0 + srow) * 512 + shalf * 16;
    const unsigned short* gc = cbbf + (size_t)(k0 + srow) * 512 + shalf * 16;
    char* wA = lds +         srow * 80 + shalf * 32;
    char* wB = lds + 10240 + srow * 80 + shalf * 32;
    const int fro = (lane & 15) * 80 + (lane >> 4) * 16;

#pragma unroll 1
    for (int kk = 0; kk < 16; ++kk) {
        uint4 vz0 = *reinterpret_cast<const uint4*>(gz + kk * 32);
        uint4 vz1 = *reinterpret_cast<const uint4*>(gz + kk * 32 + 8);
        uint4 vc0 = *reinterpret_cast<const uint4*>(gc + kk * 32);
        uint4 vc1 = *reinterpret_cast<const uint4*>(gc + kk * 32 + 8);
        __syncthreads();
        *reinterpret_cast<uint4*>(wA)      = vz0;
        *reinterpret_cast<uint4*>(wA + 16) = vz1;
        *reinterpret_cast<uint4*>(wB)      = vc0;
        *reinterpret_cast<uint4*>(wB + 16) = vc1;
        __syncthreads();

        bf16x8 af[4], bfr[4];
#pragma unroll
        for (int m = 0; m < 4; ++m)
            af[m] = *reinterpret_cast<const bf16x8*>(
                lds + (wr * 64 + m * 16) * 80 + fro);
#pragma unroll
        for (int n = 0; n < 4; ++n)
            bfr[n] = *reinterpret_cast<const bf16x8*>(
                lds + 10240 + (wc * 64 + n * 16) * 80 + fro);
#pragma unroll
        for (int m = 0; m < 4; ++m)
#pragma unroll
            for (int n = 0; n < 4; ++n)
                acc[m][n] = __builtin_amdgcn_mfma_f32_16x16x32_bf16(
                    af[m], bfr[n], acc[m][n], 0, 0, 0);
    }

    float csq[4];
#pragma unroll
    for (int n = 0; n < 4; ++n)
        csq[n] = c_sq[k0 + wc * 64 + n * 16 + (lane & 15)];

    float mn[16];
#pragma unroll
    for (int m = 0; m < 4; ++m) {
#pragma unroll
        for (int r = 0; r < 4; ++r) {
            float v = fmaf(-2.f, acc[m][0][r], csq[0]);
            v = fminf(v, fmaf(-2.f, acc[m][1][r], csq[1]));
            v = fminf(v, fmaf(-2.f, acc[m][2][r], csq[2]));
            v = fminf(v, fmaf(-2.f, acc[m][3][r], csq[3]));
#pragma unroll
            for (int off = 1; off <= 8; off <<= 1)
                v = fminf(v, __shfl_xor(v, off));
            mn[m * 4 + r] = v;
        }
    }
    if ((lane & 15) == 0) {
#pragma unroll
        for (int m = 0; m < 4; ++m)
#pragma unroll
            for (int r = 0; r < 4; ++r)
                partials[(size_t)(b0 + wr * 64 + m * 16 + (lane >> 4) * 4 + r) * 128
                         + cb * 2 + wc] = mn[m * 4 + r];
    }
}

// ---------------------------------------------------------------------------
// transpose: cbT4[dg][k] = (float4)codebook[k][dg*4..+3], dg 0..127.
// Runs AFTER gemm (overwrites the dead z_bf region). Writes coalesced
// (64 lanes x 16B contiguous over k); reads served by L2/L3 (16 MB).
// ---------------------------------------------------------------------------
__global__ __launch_bounds__(256)
void transpose_kernel(const float* __restrict__ codebook,
                      float4* __restrict__ cbT4)
{
    const int kpart = blockIdx.x & 31;          // k block (256 rows)
    const int dpart = blockIdx.x >> 5;          // 0..15 -> 8 dgroups each
    const int k = kpart * 256 + threadIdx.x;
#pragma unroll
    for (int i = 0; i < 8; ++i) {
        const int dg = dpart * 8 + i;
        float4 v = *reinterpret_cast<const float4*>(
            codebook + (size_t)k * D_SZ + dg * 4);
        cbT4[(size_t)dg * K_SZ + k] = v;
    }
}

// ---------------------------------------------------------------------------
// reduce2 (pass A): count flagged subgroups per g; init slots.
// ---------------------------------------------------------------------------
__global__ __launch_bounds__(256)
void reduce2_kernel(const float* __restrict__ partials,
                    const float* __restrict__ z_sq,
                    const float* __restrict__ maxcsq,
                    int* __restrict__ gcnt,
                    unsigned long long* __restrict__ slots)
{
    const int row  = blockIdx.x * 4 + (threadIdx.x >> 6);
    const int lane = threadIdx.x & 63;
    const float p0 = partials[(size_t)row * 128 + lane];
    const float p1 = partials[(size_t)row * 128 + 64 + lane];
    float m = fminf(p0, p1);
#pragma unroll
    for (int off = 1; off <= 32; off <<= 1) m = fminf(m, __shfl_xor(m, off));
    const float thr = 0.0225f * sqrtf(z_sq[row] * maxcsq[0]) + 0.3f;
    const float lim = m + thr;
    if (lane == 0) slots[row] = 0xFFFFFFFFFFFFFFFFull;
    if (p0 <= lim) atomicAdd(gcnt + lane, 1);
    if (p1 <= lim) atomicAdd(gcnt + 64 + lane, 1);
}

// ---------------------------------------------------------------------------
__global__ void scan_kernel(const int* __restrict__ gcnt,
                            int* __restrict__ cursor,
                            int* __restrict__ wl_count) {
    if (threadIdx.x == 0 && blockIdx.x == 0) {
        int run = 0;
        for (int g = 0; g < 128; ++g) { cursor[g] = run; run += gcnt[g]; }
        wl_count[0] = run;
    }
}

// ---------------------------------------------------------------------------
__global__ __launch_bounds__(256)
void place_kernel(const float* __restrict__ partials,
                  const float* __restrict__ z_sq,
                  const float* __restrict__ maxcsq,
                  int* __restrict__ cursor,
                  int* __restrict__ wl)
{
    const int row  = blockIdx.x * 4 + (threadIdx.x >> 6);
    const int lane = threadIdx.x & 63;
    const float p0 = partials[(size_t)row * 128 + lane];
    const float p1 = partials[(size_t)row * 128 + 64 + lane];
    float m = fminf(p0, p1);
#pragma unroll
    for (int off = 1; off <= 32; off <<= 1) m = fminf(m, __shfl_xor(m, off));
    const float thr = 0.0225f * sqrtf(z_sq[row] * maxcsq[0]) + 0.3f;
    const float lim = m + thr;
    if (p0 <= lim) {
        int pos = atomicAdd(cursor + lane, 1);
        if (pos < WL_CAP) wl[pos] = row * 128 + lane;
    }
    if (p1 <= lim) {
        int pos = atomicAdd(cursor + 64 + lane, 1);
        if (pos < WL_CAP) wl[pos] = row * 128 + 64 + lane;
    }
}

// ---------------------------------------------------------------------------
// rescore (R9): direct coalesced reads of the pre-transposed codebook.
// Lane l scores candidate kb+l: for dg 0..127, cv = cbT4[dg][kb+l] is a
// fully-coalesced 1 KB wave load (L2-resident via g-bucketed worklist);
// z via per-wave LDS broadcast. Zero per-chunk LDS staging/transpose.
// Chain: acc = fmaf(z[d], c[d], acc), d = dg*4+j strictly ascending ->
// identical to R2/R7/R8 -> identical indices.
// ---------------------------------------------------------------------------
__global__ __launch_bounds__(256, 2)
void rescore_kernel(const float* __restrict__ z_e,
                    const float4* __restrict__ cbT4,
                    const float* __restrict__ c_sq,
                    const float* __restrict__ z_sq,
                    const int* __restrict__ wl_count,
                    const int* __restrict__ wl,
                    unsigned long long* __restrict__ slots)
{
    __shared__ float zl[4][512];
    const int tid = threadIdx.x, wid = tid >> 6, lane = tid & 63;
    const int nwaves = gridDim.x * 4;
    const int wgid = blockIdx.x * 4 + wid;
    const int total = wl_count[0];

    for (int i = wgid; i < total; i += nwaves) {
        const int e = wl[i];
        const int row = e >> 7;
        const int kb = (e & 127) * 64;
        {
            float4 a = *reinterpret_cast<const float4*>(z_e + (size_t)row * 512 + lane * 8);
            float4 b = *reinterpret_cast<const float4*>(z_e + (size_t)row * 512 + lane * 8 + 4);
            *reinterpret_cast<float4*>(&zl[wid][lane * 8])     = a;
            *reinterpret_cast<float4*>(&zl[wid][lane * 8 + 4]) = b;
        }
        const float4* cp = cbT4 + kb + lane;
        float acc = 0.f;
#pragma unroll 8
        for (int dg = 0; dg < 128; ++dg) {
            const float4 cv = cp[(size_t)dg * K_SZ];
            const float4 zv = *reinterpret_cast<const float4*>(&zl[wid][dg * 4]);
            acc = fmaf(zv.x, cv.x, acc);
            acc = fmaf(zv.y, cv.y, acc);
            acc = fmaf(zv.z, cv.z, acc);
            acc = fmaf(zv.w, cv.w, acc);
        }
        float v = fmaf(-2.f, acc, z_sq[row]) + c_sq[kb + lane];
        int idx = kb + lane;
#pragma unroll
        for (int off = 1; off <= 32; off <<= 1) {
            float v2 = __shfl_xor(v, off);
            int   i2 = __shfl_xor(idx, off);
            if (v2 < v || (v2 == v && i2 < idx)) { v = v2; idx = i2; }
        }
        if (lane == 0)
            atomicMin(slots + row,
                      ((unsigned long long)__float_as_uint(v) << 32) | (unsigned)idx);
    }
}

// ---------------------------------------------------------------------------
__global__ __launch_bounds__(256)
void scatter_kernel(const float* __restrict__ z_e,
                    const float* __restrict__ codebook,
                    const unsigned long long* __restrict__ slots,
                    float* __restrict__ z_q,
                    float* __restrict__ o_idx,
                    float* __restrict__ o_ncs,
                    float* __restrict__ o_nemcb)
{
    const int wave = threadIdx.x >> 6;
    const int lane = threadIdx.x & 63;
    const int b = blockIdx.x * 4 + wave;
    const int idx = (int)(unsigned)(slots[b] & 0xFFFFFFFFull);
#pragma unroll
    for (int i = 0; i < 2; ++i) {
        int d = i * 256 + lane * 4;
        float4 cq = *reinterpret_cast<const float4*>(
            codebook + (size_t)idx * D_SZ + d);
        *reinterpret_cast<float4*>(z_q + (size_t)b * D_SZ + d) = cq;
        float4 zv = *reinterpret_cast<const float4*>(
            z_e + (size_t)b * D_SZ + d);
        atomicAdd(o_nemcb + (size_t)idx * D_SZ + d + 0, OMD * zv.x);
        atomicAdd(o_nemcb + (size_t)idx * D_SZ + d + 1, OMD * zv.y);
        atomicAdd(o_nemcb + (size_t)idx * D_SZ + d + 2, OMD * zv.z);
        atomicAdd(o_nemcb + (size_t)idx * D_SZ + d + 3, OMD * zv.w);
    }
    if (lane == 0) {
        atomicAdd(o_ncs + idx, OMD);
        o_idx[b] = (float)idx;
    }
}

// ---------------------------------------------------------------------------
__global__ __launch_bounds__(256)
void finalize_kernel(const float* __restrict__ o_nemcb,
                     const float* __restrict__ o_ncs,
                     float* __restrict__ o_ncb)
{
    const size_t i = (size_t)blockIdx.x * 256 + threadIdx.x;
    const int k = (int)(i >> 7);
    float4 nem = *reinterpret_cast<const float4*>(o_nemcb + i * 4);
    float den = o_ncs[k] + EPS;
    float4 ncb;
    ncb.x = nem.x / den; ncb.y = nem.y / den;
    ncb.z = nem.z / den; ncb.w = nem.w / den;
    *reinterpret_cast<float4*>(o_ncb + i * 4) = ncb;
}

// ---------------------------------------------------------------------------
extern "C" void kernel_launch(void* const* d_in, const int* in_sizes, int n_in,
                              void* d_out, int out_size, void* d_ws, size_t ws_size,
                              hipStream_t stream) {
    const float* z_e      = (const float*)d_in[0];   // (B, D)
    const float* codebook = (const float*)d_in[1];   // (K, D)
    const float* ema_cs   = (const float*)d_in[2];   // (K,)
    const float* ema_cb   = (const float*)d_in[3];   // (K, D)

    float* out = (float*)d_out;
    float* o_zq    = out;                                  // B*D
    float* o_idx   = out + (size_t)B_SZ * D_SZ;            // B
    float* o_ncb   = o_idx + B_SZ;                         // K*D
    float* o_ncs   = o_ncb + (size_t)K_SZ * D_SZ;          // K
    float* o_nemcb = o_ncs + K_SZ;                         // K*D

    // scratch views
    unsigned short* w_zbf  = (unsigned short*)(o_zq + ZQF_ZBF);
    unsigned short* w_cbbf = (unsigned short*)(o_zq + ZQF_CBBF);
    float4*         w_cbt  = (float4*)(o_zq + ZQF_CBT);    // after gemm
    float*          w_part = o_zq + ZQF_PART;
    float*          w_csq  = o_ncb + NCF_CSQ;
    float*          w_zsq  = o_ncb + NCF_ZSQ;
    float*          w_maxc = o_ncb + NCF_MAXC;
    int*            w_cnt  = (int*)(o_ncb + NCF_WLCNT);
    int*            w_gcnt = (int*)(o_ncb + NCF_GCNT);
    int*            w_cur  = (int*)(o_ncb + NCF_CUR);
    unsigned long long* w_slots = (unsigned long long*)(o_ncb + NCF_SLOTS);
    int*            w_wl   = (int*)(o_ncb + NCF_WL);

    rowsq_kernel<<<K_SZ / 4, 256, 0, stream>>>(codebook, w_csq);
    rowsq_kernel<<<B_SZ / 4, 256, 0, stream>>>(z_e, w_zsq);
    maxinit_kernel<<<1, 256, 0, stream>>>(w_csq, w_maxc, w_cnt, w_gcnt);
    cvt_kernel<<<(int)((size_t)B_SZ * D_SZ / 2048), 256, 0, stream>>>(z_e, w_zbf);
    cvt_kernel<<<(int)((size_t)K_SZ * D_SZ / 2048), 256, 0, stream>>>(codebook, w_cbbf);
    init_ema_kernel<<<K_SZ * D_SZ / 4 / 256, 256, 0, stream>>>(
        ema_cb, ema_cs, o_nemcb, o_ncs);
    gemm_approx<<<(B_SZ / 128) * (K_SZ / 128), 256, 0, stream>>>(
        w_zbf, w_cbbf, w_csq, w_part);
    transpose_kernel<<<512, 256, 0, stream>>>(codebook, w_cbt);  // z_bf dead now
    reduce2_kernel<<<B_SZ / 4, 256, 0, stream>>>(
        w_part, w_zsq, w_maxc, w_gcnt, w_slots);
    scan_kernel<<<1, 64, 0, stream>>>(w_gcnt, w_cur, w_cnt);
    place_kernel<<<B_SZ / 4, 256, 0, stream>>>(
        w_part, w_zsq, w_maxc, w_cur, w_wl);
    rescore_kernel<<<2048, 256, 0, stream>>>(
        z_e, w_cbt, w_csq, w_zsq, w_cnt, w_wl, w_slots);
    scatter_kernel<<<B_SZ / 4, 256, 0, stream>>>(
        z_e, codebook, w_slots, o_zq, o_idx, o_ncs, o_nemcb);
    finalize_kernel<<<K_SZ * D_SZ / 4 / 256, 256, 0, stream>>>(
        o_nemcb, o_ncs, o_ncb);
}